// Round 2
// baseline (547.565 us; speedup 1.0000x reference)
//
#include <hip/hip_runtime.h>
#include <stdint.h>

#define L_SEQ 2048
#define S_SEQ 2048
#define NB 2
#define EMB 1024
#define NH 16
#define DH 64
#define NC 32
#define MROWS 4096  // L*NB

typedef __bf16 bf16x8 __attribute__((ext_vector_type(8)));
typedef float f32x4 __attribute__((ext_vector_type(4)));

__device__ __forceinline__ float bf2f(unsigned short u) {
  return __builtin_bit_cast(float, (uint32_t)u << 16);
}
__device__ __forceinline__ unsigned short f2bf(float f) {
  uint32_t u = __builtin_bit_cast(uint32_t, f);
  return (unsigned short)((u + 0x7FFFu + ((u >> 16) & 1u)) >> 16);
}

// C = A @ B^T + bias. MFMA bf16, 128x128 tile (m93/m97-validated structure).
// A_BF16: 0 = A is f32 global (inline RNE convert), 1 = A is bf16 workspace.
// B always f32 global (inline convert). Out: f32 if outF, else bf16 outB.
template <int A_BF16>
__global__ void __launch_bounds__(256) gemm_bt_mfma(
    const void* __restrict__ Av, const float* __restrict__ B,
    const float* __restrict__ bias,
    float* __restrict__ outF, unsigned short* __restrict__ outB)
{
  __shared__ __align__(16) unsigned short As[128][32];  // unpadded 64B rows (b128-aligned)
  __shared__ __align__(16) unsigned short Bs[128][32];
  const int K = EMB;
  int tid = threadIdx.x;
  int m0 = blockIdx.y * 128, n0 = blockIdx.x * 128;
  int wave = tid >> 6, lane = tid & 63;
  int wm = (wave >> 1) * 64, wn = (wave & 1) * 64;

  f32x4 zero = {0.f, 0.f, 0.f, 0.f};
  f32x4 acc[4][4];
#pragma unroll
  for (int mi = 0; mi < 4; mi++)
#pragma unroll
    for (int ni = 0; ni < 4; ni++) acc[mi][ni] = zero;

  int fr = lane & 15, fk = (lane >> 4) * 8;

  for (int k0 = 0; k0 < K; k0 += 32) {
    __syncthreads();
#pragma unroll
    for (int it = 0; it < 2; it++) {
      int ch = tid + it * 256;          // 512 chunks of 8 elems per tile
      int row = ch >> 2, kk = (ch & 3) * 8;
      if (A_BF16) {
        const unsigned short* ap = (const unsigned short*)Av + (size_t)(m0 + row) * K + k0 + kk;
        *(uint4*)(&As[row][kk]) = *(const uint4*)ap;
      } else {
        const float* ap = (const float*)Av + (size_t)(m0 + row) * K + k0 + kk;
        float4 a0 = *(const float4*)ap, a1 = *(const float4*)(ap + 4);
        uint4 u;
        u.x = (uint32_t)f2bf(a0.x) | ((uint32_t)f2bf(a0.y) << 16);
        u.y = (uint32_t)f2bf(a0.z) | ((uint32_t)f2bf(a0.w) << 16);
        u.z = (uint32_t)f2bf(a1.x) | ((uint32_t)f2bf(a1.y) << 16);
        u.w = (uint32_t)f2bf(a1.z) | ((uint32_t)f2bf(a1.w) << 16);
        *(uint4*)(&As[row][kk]) = u;
      }
      {
        const float* bp = B + (size_t)(n0 + row) * K + k0 + kk;
        float4 b0 = *(const float4*)bp, b1 = *(const float4*)(bp + 4);
        uint4 u;
        u.x = (uint32_t)f2bf(b0.x) | ((uint32_t)f2bf(b0.y) << 16);
        u.y = (uint32_t)f2bf(b0.z) | ((uint32_t)f2bf(b0.w) << 16);
        u.z = (uint32_t)f2bf(b1.x) | ((uint32_t)f2bf(b1.y) << 16);
        u.w = (uint32_t)f2bf(b1.z) | ((uint32_t)f2bf(b1.w) << 16);
        *(uint4*)(&Bs[row][kk]) = u;
      }
    }
    __syncthreads();
    bf16x8 af[4], bfr[4];
#pragma unroll
    for (int i = 0; i < 4; i++) af[i] = *(const bf16x8*)(&As[wm + i * 16 + fr][fk]);
#pragma unroll
    for (int i = 0; i < 4; i++) bfr[i] = *(const bf16x8*)(&Bs[wn + i * 16 + fr][fk]);
#pragma unroll
    for (int mi = 0; mi < 4; mi++)
#pragma unroll
      for (int ni = 0; ni < 4; ni++)
        acc[mi][ni] = __builtin_amdgcn_mfma_f32_16x16x32_bf16(af[mi], bfr[ni], acc[mi][ni], 0, 0, 0);
  }

#pragma unroll
  for (int ni = 0; ni < 4; ni++) {
    int col = n0 + wn + ni * 16 + (lane & 15);
    float bv = bias[col];
#pragma unroll
    for (int mi = 0; mi < 4; mi++) {
#pragma unroll
      for (int r = 0; r < 4; r++) {
        int row = m0 + wm + mi * 16 + (lane >> 4) * 4 + r;
        float v = acc[mi][ni][r] + bv;
        if (outF) outF[(size_t)row * EMB + col] = v;
        else outB[(size_t)row * EMB + col] = f2bf(v);
      }
    }
  }
}

// WcT[k][c] = sum_e W[e][k]*cent[c][e]; bd[c] = sum_e bias[e]*cent[c][e]; f64 (exact reassociation:
// (x@W^T+b)·cent_c = sum_k x_k*WcT[k][c] + bd[c]). Inputs f32. TRANSPOSED layout so assignment
// loads are lane-coalesced (lane=c reads 256 contiguous bytes).
__global__ void __launch_bounds__(256) prep_wc_kernel(
    const float* __restrict__ W, const float* __restrict__ bias,
    const float* __restrict__ cent,
    double* __restrict__ WcT, double* __restrict__ bd)
{
  int k = blockIdx.x;
  int tid = threadIdx.x;
  int c = tid & 31, g = tid >> 5;
  __shared__ double red[8][32];
  double s = 0.0;
  for (int e = g * 128; e < (g + 1) * 128; e++)
    s += (double)W[(size_t)e * EMB + k] * (double)cent[(size_t)c * EMB + e];
  red[g][c] = s;
  __syncthreads();
  if (tid < 32) {
    double t = 0.0;
#pragma unroll
    for (int gg = 0; gg < 8; gg++) t += red[gg][tid];
    WcT[(size_t)k * NC + tid] = t;
  }
  if (k == 0) {
    __syncthreads();
    double s2 = 0.0;
    for (int e = g * 128; e < (g + 1) * 128; e++)
      s2 += (double)bias[e] * (double)cent[(size_t)c * EMB + e];
    red[g][c] = s2;
    __syncthreads();
    if (tid < 32) {
      double t = 0.0;
#pragma unroll
      for (int gg = 0; gg < 8; gg++) t += red[gg][tid];
      bd[tid] = t;
    }
  }
}

// Assignment from RAW f32 input rows via WcT: f64 dots, first-max argmax.
// Thread (g=row, c=cluster): 8 rows/block, lanes 0-31 = clusters. X rows staged in LDS
// (broadcast reads); WcT[k][c] loads coalesced across lanes. 8 independent f64
// accumulator chains; argmax via shfl_xor (val,idx) reduce with first-max ties.
// blockIdx.y: 0 = query set, 1 = key set (merged launch for occupancy).
__global__ void __launch_bounds__(256, 4) assign2_kernel(
    const float* __restrict__ Xq, const double* __restrict__ WcTq, const double* __restrict__ bdq,
    int* __restrict__ qcl, int* __restrict__ qcnt,
    const float* __restrict__ Xk, const double* __restrict__ WcTk, const double* __restrict__ bdk,
    int* __restrict__ kcl, int* __restrict__ kcnt)
{
  const float* X; const double* WcT; const double* bd; int* cluster; int* count;
  if (blockIdx.y == 0) { X = Xq; WcT = WcTq; bd = bdq; cluster = qcl; count = qcnt; }
  else                 { X = Xk; WcT = WcTk; bd = bdk; cluster = kcl; count = kcnt; }

  int r0 = blockIdx.x * 8;
  int tid = threadIdx.x;
  __shared__ __align__(16) float Xs[8][EMB];   // 32 KB

#pragma unroll
  for (int it = 0; it < 8; it++) {
    int idx = it * 256 + tid;                  // 2048 float4 pieces
    int row = idx >> 8, col = (idx & 255) * 4;
    *(float4*)(&Xs[row][col]) = *(const float4*)(X + (size_t)(r0 + row) * EMB + col);
  }
  __syncthreads();

  int c = tid & 31, g = tid >> 5;
  const double* wp = WcT + c;
  double a0 = 0, a1 = 0, a2 = 0, a3 = 0, a4 = 0, a5 = 0, a6 = 0, a7 = 0;
  for (int k = 0; k < EMB; k += 8) {
    double w0 = wp[(size_t)(k + 0) * NC], w1 = wp[(size_t)(k + 1) * NC];
    double w2 = wp[(size_t)(k + 2) * NC], w3 = wp[(size_t)(k + 3) * NC];
    double w4 = wp[(size_t)(k + 4) * NC], w5 = wp[(size_t)(k + 5) * NC];
    double w6 = wp[(size_t)(k + 6) * NC], w7 = wp[(size_t)(k + 7) * NC];
    float4 x0 = *(const float4*)(&Xs[g][k]);
    float4 x1 = *(const float4*)(&Xs[g][k + 4]);
    a0 += (double)x0.x * w0;
    a1 += (double)x0.y * w1;
    a2 += (double)x0.z * w2;
    a3 += (double)x0.w * w3;
    a4 += (double)x1.x * w4;
    a5 += (double)x1.y * w5;
    a6 += (double)x1.z * w6;
    a7 += (double)x1.w * w7;
  }
  double dot = (((a0 + a1) + (a2 + a3)) + ((a4 + a5) + (a6 + a7))) + bd[c];

  // argmax over c within each 32-lane half (first-max: lowest index wins ties)
  double bv = dot;
  int bi = c;
#pragma unroll
  for (int off = 1; off < 32; off <<= 1) {
    double ov = __shfl_xor(bv, off, 64);
    int oi = __shfl_xor(bi, off, 64);
    if (ov > bv || (ov == bv && oi < bi)) { bv = ov; bi = oi; }
  }
  if (c == 0) {
    int row = r0 + g;
    cluster[row] = bi;
    atomicAdd(&count[(row & 1) * NC + bi], 1);
  }
}

__global__ void scan_kernel(const int* __restrict__ qcount, const int* __restrict__ kcount,
                            int* __restrict__ qoff, int* __restrict__ koff)
{
  int tid = threadIdx.x;
  if (tid < 2) {
    int run = 0;
    for (int c = 0; c < NC; c++) { qoff[tid * NC + c] = run; run += qcount[tid * NC + c]; }
  } else if (tid < 4) {
    int n = tid - 2, run = 0;
    for (int c = 0; c < NC; c++) { koff[n * NC + c] = run; run += kcount[n * NC + c]; }
  }
}

__global__ void __launch_bounds__(256) scatter_kernel(
    const int* __restrict__ q_cluster, const int* __restrict__ k_cluster,
    const int* __restrict__ qoff, const int* __restrict__ koff,
    int* __restrict__ qfill, int* __restrict__ kfill,
    int* __restrict__ qlist, int* __restrict__ klist)
{
  int id = blockIdx.x * 256 + threadIdx.x;
  if (id < MROWS) {
    int row = id, n = row & 1, l = row >> 1, c = q_cluster[row];
    int pos = atomicAdd(&qfill[n * NC + c], 1);
    qlist[n * L_SEQ + qoff[n * NC + c] + pos] = l;
  } else {
    int row = id - MROWS, n = row & 1, s = row >> 1, c = k_cluster[row];
    int pos = atomicAdd(&kfill[n * NC + c], 1);
    klist[n * S_SEQ + koff[n * NC + c] + pos] = s;
  }
}

// Bucketed attention, MFMA flash-style. Block=(cluster,head,batch), 4 waves, 16 queries/wave,
// 64-key chunks with online softmax. Swapped operands keep softmax per-lane-uniform:
//   S^T = mfma(A=K, B=Q)    -> D[row=key=4g+r][col=q=lane&15]
//   O^T = mfma(A=V^T, B=P^T)-> D[row=d  =4g+r][col=q=lane&15]
// so running max / lsum / rescale are one scalar per lane (reduce = shfl_xor 16,32).
// P^T relayout through wave-private LDS: C-frag writes 4 consecutive keys (ds_write_b64),
// B-frag reads 8 consecutive keys (ds_read_b128). All LDS tiles row-XOR-swizzled
// (elem_col ^= (row&7)<<3, i.e. byte ^= (row&7)<<4) to kill the 16-way b128 bank conflict.
// Frag addressing pattern identical to gemm_bt_mfma above (harness-validated layout).
__global__ void __launch_bounds__(256) attn_bucket(
    const unsigned short* __restrict__ Qb, const unsigned short* __restrict__ Kb,
    const unsigned short* __restrict__ Vb,
    const int* __restrict__ qcount, const int* __restrict__ qoff, const int* __restrict__ qlist,
    const int* __restrict__ kcount, const int* __restrict__ koff, const int* __restrict__ klist,
    unsigned short* __restrict__ ctx)
{
  int c = blockIdx.x, h = blockIdx.y, n = blockIdx.z;
  int Sc = kcount[n * NC + c], k0base = koff[n * NC + c];
  int Lc = qcount[n * NC + c], q0 = qoff[n * NC + c];
  int tid = threadIdx.x, wave = tid >> 6, lane = tid & 63;
  int lg = lane >> 4, lq = lane & 15;

  __shared__ __align__(16) unsigned short Ks[64][64];    // [key][d], row-swizzled
  __shared__ __align__(16) unsigned short Vts[64][64];   // [d][key], row-swizzled
  __shared__ __align__(16) unsigned short Pts[4][16][64]; // per-wave [q][key], row-swizzled
  __shared__ int rb[64];                                  // gathered K/V row base offsets

  if (Sc == 0) {   // no keys: ref softmax would be NaN; R9 proved this never occurs. Write 0.
    for (int qi = wave; qi < Lc; qi += 4) {
      int l = qlist[n * L_SEQ + q0 + qi];
      ctx[((size_t)(n * L_SEQ + l)) * EMB + h * DH + lane] = 0;
    }
    return;
  }

  const int* kl = klist + n * S_SEQ + k0base;
  const int* ql = qlist + n * L_SEQ + q0;
  f32x4 zero = {0.f, 0.f, 0.f, 0.f};

  for (int qb = 0; qb < Lc; qb += 64) {           // uniform trip count across waves
    int qq = qb + wave * 16 + lq;
    int qqc = qq < Lc ? qq : Lc - 1;              // clamp: padded lanes duplicate last query
    int lrow = ql[qqc];
    const unsigned short* qp = Qb + ((size_t)(lrow * NB + n)) * EMB + h * DH;
    bf16x8 qf0 = *(const bf16x8*)(qp + lg * 8);          // B=Q frag: col=q, k=d 0..31
    bf16x8 qf1 = *(const bf16x8*)(qp + 32 + lg * 8);     //                  d 32..63

    f32x4 acc[4];                                  // O^T: 4 d-tiles, col=q per lane
#pragma unroll
    for (int di = 0; di < 4; di++) acc[di] = zero;
    float m = -3.0e38f, lsum = 0.f;

    for (int kc = 0; kc < Sc; kc += 64) {
      __syncthreads();                             // prev chunk compute done
      if (tid < 64) {
        int jj = kc + tid; if (jj >= Sc) jj = Sc - 1;   // clamp-pad: valid finite rows
        rb[tid] = (kl[jj] * NB + n) * EMB + h * DH;
      }
      __syncthreads();                             // rb ready
#pragma unroll
      for (int it = 0; it < 2; it++) {
        int p = it * 256 + tid;                    // 512 pieces
        {                                          // K: [key][d] 16B pieces
          int row = p >> 3, seg = p & 7;
          uint4 u = *(const uint4*)(Kb + rb[row] + seg * 8);
          *(uint4*)(&Ks[row][(seg * 8) ^ ((row & 7) << 3)]) = u;
        }
        {                                          // V^T: gather column d, 8 keys
          int d = p & 63, kg = p >> 6;
          unsigned short v0 = Vb[rb[kg * 8 + 0] + d], v1 = Vb[rb[kg * 8 + 1] + d];
          unsigned short v2 = Vb[rb[kg * 8 + 2] + d], v3 = Vb[rb[kg * 8 + 3] + d];
          unsigned short v4 = Vb[rb[kg * 8 + 4] + d], v5 = Vb[rb[kg * 8 + 5] + d];
          unsigned short v6 = Vb[rb[kg * 8 + 6] + d], v7 = Vb[rb[kg * 8 + 7] + d];
          uint4 u;
          u.x = (uint32_t)v0 | ((uint32_t)v1 << 16);
          u.y = (uint32_t)v2 | ((uint32_t)v3 << 16);
          u.z = (uint32_t)v4 | ((uint32_t)v5 << 16);
          u.w = (uint32_t)v6 | ((uint32_t)v7 << 16);
          *(uint4*)(&Vts[d][(kg * 8) ^ ((d & 7) << 3)]) = u;
        }
      }
      __syncthreads();                             // K/V^T staged

      // S^T = K @ Q^T : 4 key-tiles x 2 d-steps
      f32x4 st[4];
#pragma unroll
      for (int ni = 0; ni < 4; ni++) st[ni] = zero;
#pragma unroll
      for (int ni = 0; ni < 4; ni++) {
        int row = ni * 16 + lq;
        bf16x8 kf0 = *(const bf16x8*)(&Ks[row][(lg * 8) ^ ((row & 7) << 3)]);
        bf16x8 kf1 = *(const bf16x8*)(&Ks[row][(32 + lg * 8) ^ ((row & 7) << 3)]);
        st[ni] = __builtin_amdgcn_mfma_f32_16x16x32_bf16(kf0, qf0, st[ni], 0, 0, 0);
        st[ni] = __builtin_amdgcn_mfma_f32_16x16x32_bf16(kf1, qf1, st[ni], 0, 0, 0);
      }

      // online softmax (per-lane scalar state; clamp-padded keys duplicate valid
      // scores so they cannot change the max; they are zeroed in p below)
      int lim = Sc - kc;
      float cm = -3.0e38f;
#pragma unroll
      for (int ni = 0; ni < 4; ni++) {
        st[ni] = st[ni] * 0.125f;                  // 1/sqrt(64)
#pragma unroll
        for (int r = 0; r < 4; r++) cm = fmaxf(cm, st[ni][r]);
      }
      cm = fmaxf(cm, __shfl_xor(cm, 16, 64));
      cm = fmaxf(cm, __shfl_xor(cm, 32, 64));
      float mn = fmaxf(m, cm);
      float fac = __expf(m - mn);
      m = mn;
      lsum *= fac;
#pragma unroll
      for (int di = 0; di < 4; di++) acc[di] = acc[di] * fac;

      // P^T -> LDS (bf16); lsum over ROUNDED p so O stays a true weighted average
#pragma unroll
      for (int ni = 0; ni < 4; ni++) {
        int kloc = ni * 16 + lg * 4;
        float p0 = (kloc + 0 < lim) ? __expf(st[ni][0] - mn) : 0.f;
        float p1 = (kloc + 1 < lim) ? __expf(st[ni][1] - mn) : 0.f;
        float p2 = (kloc + 2 < lim) ? __expf(st[ni][2] - mn) : 0.f;
        float p3 = (kloc + 3 < lim) ? __expf(st[ni][3] - mn) : 0.f;
        unsigned short b0 = f2bf(p0), b1 = f2bf(p1), b2 = f2bf(p2), b3 = f2bf(p3);
        lsum += bf2f(b0) + bf2f(b1) + bf2f(b2) + bf2f(b3);
        ushort4 u4; u4.x = b0; u4.y = b1; u4.z = b2; u4.w = b3;
        *(ushort4*)(&Pts[wave][lq][kloc ^ ((lq & 7) << 3)]) = u4;
      }

      // O^T += V^T @ P^T : 4 d-tiles x 2 key-steps
#pragma unroll
      for (int ks = 0; ks < 2; ks++) {
        bf16x8 pf = *(const bf16x8*)(&Pts[wave][lq][(ks * 32 + lg * 8) ^ ((lq & 7) << 3)]);
#pragma unroll
        for (int di = 0; di < 4; di++) {
          int row = di * 16 + lq;
          bf16x8 vf = *(const bf16x8*)(&Vts[row][(ks * 32 + lg * 8) ^ ((row & 7) << 3)]);
          acc[di] = __builtin_amdgcn_mfma_f32_16x16x32_bf16(vf, pf, acc[di], 0, 0, 0);
        }
      }
    }

    lsum += __shfl_xor(lsum, 16, 64);
    lsum += __shfl_xor(lsum, 32, 64);
    float rinv = 1.f / lsum;
    if (qq < Lc) {                                 // padded duplicates skip the store
      unsigned short* op = ctx + ((size_t)(n * L_SEQ + lrow)) * EMB + h * DH;
#pragma unroll
      for (int di = 0; di < 4; di++) {
        ushort4 o;
        o.x = f2bf(acc[di][0] * rinv);
        o.y = f2bf(acc[di][1] * rinv);
        o.z = f2bf(acc[di][2] * rinv);
        o.w = f2bf(acc[di][3] * rinv);
        *(ushort4*)(op + di * 16 + lg * 4) = o;    // d = di*16 + 4g + r, contiguous r
      }
    }
  }
}

// Residual + LayerNorm, f32 output. out row r = l*NB+n; proj row = n*L+l. (R9-validated.)
__global__ void __launch_bounds__(256) ln_kernel(
    const float* __restrict__ proj, const float* __restrict__ query,
    const float* __restrict__ gamma, const float* __restrict__ beta,
    float* __restrict__ out)
{
  int r = blockIdx.x;
  int l = r >> 1, n = r & 1;
  int tid = threadIdx.x, wave = tid >> 6, lane = tid & 63;
  float4 p = *(const float4*)(proj + ((size_t)(n * L_SEQ + l)) * EMB + tid * 4);
  float4 qu = *(const float4*)(query + (size_t)r * EMB + tid * 4);
  float res[4] = { p.x + qu.x, p.y + qu.y, p.z + qu.z, p.w + qu.w };
  float s1 = res[0] + res[1] + res[2] + res[3];
  float s2 = res[0] * res[0] + res[1] * res[1] + res[2] * res[2] + res[3] * res[3];
#pragma unroll
  for (int off = 32; off; off >>= 1) {
    s1 += __shfl_xor(s1, off, 64);
    s2 += __shfl_xor(s2, off, 64);
  }
  __shared__ float a1[4], a2[4];
  if (lane == 0) { a1[wave] = s1; a2[wave] = s2; }
  __syncthreads();
  float t1 = a1[0] + a1[1] + a1[2] + a1[3];
  float t2 = a2[0] + a2[1] + a2[2] + a2[3];
  float mu = t1 * (1.f / EMB);
  float var = fmaxf(t2 * (1.f / EMB) - mu * mu, 0.f);
  float rstd = 1.f / sqrtf(var + 1e-5f);
  float4 gu = *(const float4*)(gamma + tid * 4);
  float4 bu = *(const float4*)(beta + tid * 4);
  float4 o;
  o.x = (res[0] - mu) * rstd * gu.x + bu.x;
  o.y = (res[1] - mu) * rstd * gu.y + bu.y;
  o.z = (res[2] - mu) * rstd * gu.z + bu.z;
  o.w = (res[3] - mu) * rstd * gu.w + bu.w;
  *(float4*)(out + (size_t)r * EMB + tid * 4) = o;
}

extern "C" void kernel_launch(void* const* d_in, const int* in_sizes, int n_in,
                              void* d_out, int out_size, void* d_ws, size_t ws_size,
                              hipStream_t stream) {
  const float* query = (const float*)d_in[0];
  const float* key   = (const float*)d_in[1];
  const float* value = (const float*)d_in[2];
  const float* Wq = (const float*)d_in[3];
  const float* bq = (const float*)d_in[4];
  const float* Wk = (const float*)d_in[5];
  const float* bk = (const float*)d_in[6];
  const float* Wv = (const float*)d_in[7];
  const float* bv = (const float*)d_in[8];
  const float* Wo = (const float*)d_in[9];
  const float* bo = (const float*)d_in[10];
  const float* cq = (const float*)d_in[11];
  const float* ck = (const float*)d_in[12];
  const float* gamma = (const float*)d_in[13];
  const float* beta  = (const float*)d_in[14];
  float* out = (float*)d_out;   // f32 output (reference dtype)

  const size_t MB_EL = (size_t)MROWS * EMB;   // 4M elements

  // workspace (~33 MB): control block first, then bf16 tensors; proj aliases Qb+Kb.
  int* q_cluster = (int*)d_ws;               // 16 KB
  int* k_cluster = q_cluster + MROWS;        // 16 KB
  int* qcount = k_cluster + MROWS;           // 6 x 64 ints contiguous (one memset)
  int* kcount = qcount + 64;
  int* qoff   = kcount + 64;
  int* koff   = qoff + 64;
  int* qfill  = koff + 64;
  int* kfill  = qfill + 64;
  int* qlist  = kfill + 64;                  // [2][2048]
  int* klist  = qlist + MROWS;               // [2][2048]
  double* Wcq = (double*)(klist + MROWS);    // 256 KB (offset 67072, 16B-aligned) [k][c] layout
  double* Wck = Wcq + (size_t)NC * EMB;      // 256 KB [k][c] layout
  double* bdq = Wck + (size_t)NC * EMB;
  double* bdk = bdq + NC;
  unsigned short* Qb  = (unsigned short*)(bdk + NC);  // 8 MB bf16, row = seq*2+n
  unsigned short* Kb  = Qb + MB_EL;                   // 8 MB
  unsigned short* Vb  = Kb + MB_EL;                   // 8 MB
  unsigned short* ctx = Vb + MB_EL;                   // 8 MB, row = n*L+l
  float* proj = (float*)Qb;    // 16 MB f32 overlays Qb+Kb (dead after attention)

  hipMemsetAsync(qcount, 0, 6 * 64 * sizeof(int), stream);

  prep_wc_kernel<<<EMB, 256, 0, stream>>>(Wq, bq, cq, Wcq, bdq);
  prep_wc_kernel<<<EMB, 256, 0, stream>>>(Wk, bk, ck, Wck, bdk);

  dim3 gg(EMB / 128, MROWS / 128);
  gemm_bt_mfma<0><<<gg, 256, 0, stream>>>(query, Wq, bq, nullptr, Qb);
  gemm_bt_mfma<0><<<gg, 256, 0, stream>>>(key,   Wk, bk, nullptr, Kb);
  gemm_bt_mfma<0><<<gg, 256, 0, stream>>>(value, Wv, bv, nullptr, Vb);

  assign2_kernel<<<dim3(MROWS / 8, 2), 256, 0, stream>>>(
      query, Wcq, bdq, q_cluster, qcount,
      key,   Wck, bdk, k_cluster, kcount);

  scan_kernel<<<1, 64, 0, stream>>>(qcount, kcount, qoff, koff);
  scatter_kernel<<<(2 * MROWS) / 256, 256, 0, stream>>>(q_cluster, k_cluster, qoff, koff,
                                                        qfill, kfill, qlist, klist);
  attn_bucket<<<dim3(NC, NH, NB), 256, 0, stream>>>(Qb, Kb, Vb, qcount, qoff, qlist,
                                                    kcount, koff, klist, ctx);
  gemm_bt_mfma<1><<<gg, 256, 0, stream>>>(ctx, Wo, bo, proj, nullptr);
  ln_kernel<<<MROWS, 256, 0, stream>>>(proj, query, gamma, beta, out);
}

// Round 3
// 459.378 us; speedup vs baseline: 1.1920x; 1.1920x over previous
//
#include <hip/hip_runtime.h>
#include <stdint.h>

#define L_SEQ 2048
#define S_SEQ 2048
#define NB 2
#define EMB 1024
#define NH 16
#define DH 64
#define NC 32
#define MROWS 4096  // L*NB

typedef __bf16 bf16x8 __attribute__((ext_vector_type(8)));
typedef float f32x4 __attribute__((ext_vector_type(4)));

__device__ __forceinline__ float bf2f(unsigned short u) {
  return __builtin_bit_cast(float, (uint32_t)u << 16);
}
__device__ __forceinline__ unsigned short f2bf(float f) {
  uint32_t u = __builtin_bit_cast(uint32_t, f);
  return (unsigned short)((u + 0x7FFFu + ((u >> 16) & 1u)) >> 16);
}

// C = A @ B^T + bias. MFMA bf16, 128x128 tile (m93/m97-validated structure).
// A_BF16: 0 = A is f32 global (inline RNE convert), 1 = A is bf16 workspace.
// B always f32 global (inline convert). Out: f32 if outF, else bf16 outB.
template <int A_BF16>
__global__ void __launch_bounds__(256) gemm_bt_mfma(
    const void* __restrict__ Av, const float* __restrict__ B,
    const float* __restrict__ bias,
    float* __restrict__ outF, unsigned short* __restrict__ outB)
{
  __shared__ __align__(16) unsigned short As[128][32];  // unpadded 64B rows (b128-aligned)
  __shared__ __align__(16) unsigned short Bs[128][32];
  const int K = EMB;
  int tid = threadIdx.x;
  int m0 = blockIdx.y * 128, n0 = blockIdx.x * 128;
  int wave = tid >> 6, lane = tid & 63;
  int wm = (wave >> 1) * 64, wn = (wave & 1) * 64;

  f32x4 zero = {0.f, 0.f, 0.f, 0.f};
  f32x4 acc[4][4];
#pragma unroll
  for (int mi = 0; mi < 4; mi++)
#pragma unroll
    for (int ni = 0; ni < 4; ni++) acc[mi][ni] = zero;

  int fr = lane & 15, fk = (lane >> 4) * 8;

  for (int k0 = 0; k0 < K; k0 += 32) {
    __syncthreads();
#pragma unroll
    for (int it = 0; it < 2; it++) {
      int ch = tid + it * 256;          // 512 chunks of 8 elems per tile
      int row = ch >> 2, kk = (ch & 3) * 8;
      if (A_BF16) {
        const unsigned short* ap = (const unsigned short*)Av + (size_t)(m0 + row) * K + k0 + kk;
        *(uint4*)(&As[row][kk]) = *(const uint4*)ap;
      } else {
        const float* ap = (const float*)Av + (size_t)(m0 + row) * K + k0 + kk;
        float4 a0 = *(const float4*)ap, a1 = *(const float4*)(ap + 4);
        uint4 u;
        u.x = (uint32_t)f2bf(a0.x) | ((uint32_t)f2bf(a0.y) << 16);
        u.y = (uint32_t)f2bf(a0.z) | ((uint32_t)f2bf(a0.w) << 16);
        u.z = (uint32_t)f2bf(a1.x) | ((uint32_t)f2bf(a1.y) << 16);
        u.w = (uint32_t)f2bf(a1.z) | ((uint32_t)f2bf(a1.w) << 16);
        *(uint4*)(&As[row][kk]) = u;
      }
      {
        const float* bp = B + (size_t)(n0 + row) * K + k0 + kk;
        float4 b0 = *(const float4*)bp, b1 = *(const float4*)(bp + 4);
        uint4 u;
        u.x = (uint32_t)f2bf(b0.x) | ((uint32_t)f2bf(b0.y) << 16);
        u.y = (uint32_t)f2bf(b0.z) | ((uint32_t)f2bf(b0.w) << 16);
        u.z = (uint32_t)f2bf(b1.x) | ((uint32_t)f2bf(b1.y) << 16);
        u.w = (uint32_t)f2bf(b1.z) | ((uint32_t)f2bf(b1.w) << 16);
        *(uint4*)(&Bs[row][kk]) = u;
      }
    }
    __syncthreads();
    bf16x8 af[4], bfr[4];
#pragma unroll
    for (int i = 0; i < 4; i++) af[i] = *(const bf16x8*)(&As[wm + i * 16 + fr][fk]);
#pragma unroll
    for (int i = 0; i < 4; i++) bfr[i] = *(const bf16x8*)(&Bs[wn + i * 16 + fr][fk]);
#pragma unroll
    for (int mi = 0; mi < 4; mi++)
#pragma unroll
      for (int ni = 0; ni < 4; ni++)
        acc[mi][ni] = __builtin_amdgcn_mfma_f32_16x16x32_bf16(af[mi], bfr[ni], acc[mi][ni], 0, 0, 0);
  }

#pragma unroll
  for (int ni = 0; ni < 4; ni++) {
    int col = n0 + wn + ni * 16 + (lane & 15);
    float bv = bias[col];
#pragma unroll
    for (int mi = 0; mi < 4; mi++) {
#pragma unroll
      for (int r = 0; r < 4; r++) {
        int row = m0 + wm + mi * 16 + (lane >> 4) * 4 + r;
        float v = acc[mi][ni][r] + bv;
        if (outF) outF[(size_t)row * EMB + col] = v;
        else outB[(size_t)row * EMB + col] = f2bf(v);
      }
    }
  }
}

// WcT[k][c] = sum_e W[e][k]*cent[c][e]; bd[c] = sum_e bias[e]*cent[c][e]; f64 (exact reassociation:
// (x@W^T+b)·cent_c = sum_k x_k*WcT[k][c] + bd[c]). Inputs f32. [k][c] layout: coalesced for both
// assignment LDS staging and prep writes.
__global__ void __launch_bounds__(256) prep_wc_kernel(
    const float* __restrict__ W, const float* __restrict__ bias,
    const float* __restrict__ cent,
    double* __restrict__ WcT, double* __restrict__ bd)
{
  int k = blockIdx.x;
  int tid = threadIdx.x;
  int c = tid & 31, g = tid >> 5;
  __shared__ double red[8][32];
  double s = 0.0;
  for (int e = g * 128; e < (g + 1) * 128; e++)
    s += (double)W[(size_t)e * EMB + k] * (double)cent[(size_t)c * EMB + e];
  red[g][c] = s;
  __syncthreads();
  if (tid < 32) {
    double t = 0.0;
#pragma unroll
    for (int gg = 0; gg < 8; gg++) t += red[gg][tid];
    WcT[(size_t)k * NC + tid] = t;
  }
  if (k == 0) {
    __syncthreads();
    double s2 = 0.0;
    for (int e = g * 128; e < (g + 1) * 128; e++)
      s2 += (double)bias[e] * (double)cent[(size_t)c * EMB + e];
    red[g][c] = s2;
    __syncthreads();
    if (tid < 32) {
      double t = 0.0;
#pragma unroll
      for (int gg = 0; gg < 8; gg++) t += red[gg][tid];
      bd[tid] = t;
    }
  }
}

// Assignment from RAW f32 input rows via WcT: f64 dots, first-max argmax.
// LDS-tiled: block = 16 rows x 32 clusters; per 64-k chunk, stage WcT chunk (16 KB,
// natural [k][c] layout) + X rows as f64 (8 KB) in LDS; inner loop is LDS-resident
// (Ws b64 2-way-free + Xd b128 broadcast + 4 independent f64 FMA chains). Fixes R1's
// L2-latency-bound WcT stream (VALUBusy 10%, 146us). blockIdx.y: 0=query, 1=key.
__global__ void __launch_bounds__(256, 2) assign2_kernel(
    const float* __restrict__ Xq, const double* __restrict__ WcTq, const double* __restrict__ bdq,
    int* __restrict__ qcl, int* __restrict__ qcnt,
    const float* __restrict__ Xk, const double* __restrict__ WcTk, const double* __restrict__ bdk,
    int* __restrict__ kcl, int* __restrict__ kcnt)
{
  const float* X; const double* WcT; const double* bd; int* cluster; int* count;
  if (blockIdx.y == 0) { X = Xq; WcT = WcTq; bd = bdq; cluster = qcl; count = qcnt; }
  else                 { X = Xk; WcT = WcTk; bd = bdk; cluster = kcl; count = kcnt; }

  int r0 = blockIdx.x * 16;
  int tid = threadIdx.x;
  int c = tid & 31, g = tid >> 5;

  __shared__ __align__(16) double Ws[64][32];   // [kk][c], 16 KB
  __shared__ __align__(16) double Xd[16][64];   // [row][kk], 8 KB

  double aAe = 0, aAo = 0, aBe = 0, aBo = 0;    // 2 rows x (even,odd) chains

  for (int k0 = 0; k0 < EMB; k0 += 64) {
    __syncthreads();                             // prev chunk compute done
    // stage WcT chunk: 2048 doubles, 8/thread, fully coalesced (512 B / wave-instr)
#pragma unroll
    for (int it = 0; it < 8; it++) {
      int idx = it * 256 + tid;
      ((double*)Ws)[idx] = WcT[(size_t)k0 * NC + idx];
    }
    // stage X chunk as f64: 1024 floats, float2/thread x2, coalesced
#pragma unroll
    for (int it = 0; it < 2; it++) {
      int idx = it * 256 + tid;
      int r = idx >> 5, kp = idx & 31;
      float2 xv = *(const float2*)(X + (size_t)(r0 + r) * EMB + k0 + kp * 2);
      double2 xd; xd.x = (double)xv.x; xd.y = (double)xv.y;
      *(double2*)(&Xd[r][kp * 2]) = xd;
    }
    __syncthreads();                             // tiles ready
#pragma unroll
    for (int kk = 0; kk < 64; kk += 2) {
      double w0 = Ws[kk][c], w1 = Ws[kk + 1][c];
      double2 xa = *(const double2*)(&Xd[g * 2][kk]);
      double2 xb = *(const double2*)(&Xd[g * 2 + 1][kk]);
      aAe += xa.x * w0; aAo += xa.y * w1;
      aBe += xb.x * w0; aBo += xb.y * w1;
    }
  }

  double dA = (aAe + aAo) + bd[c];
  double dB = (aBe + aBo) + bd[c];

  // argmax over c within each 32-lane half, both rows (first-max: lowest index wins ties)
  double bvA = dA; int biA = c;
  double bvB = dB; int biB = c;
#pragma unroll
  for (int off = 1; off < 32; off <<= 1) {
    double ovA = __shfl_xor(bvA, off, 64); int oiA = __shfl_xor(biA, off, 64);
    if (ovA > bvA || (ovA == bvA && oiA < biA)) { bvA = ovA; biA = oiA; }
    double ovB = __shfl_xor(bvB, off, 64); int oiB = __shfl_xor(biB, off, 64);
    if (ovB > bvB || (ovB == bvB && oiB < biB)) { bvB = ovB; biB = oiB; }
  }
  if (c == 0) {
    int rowA = r0 + g * 2, rowB = rowA + 1;
    cluster[rowA] = biA; atomicAdd(&count[(rowA & 1) * NC + biA], 1);
    cluster[rowB] = biB; atomicAdd(&count[(rowB & 1) * NC + biB], 1);
  }
}

__global__ void scan_kernel(const int* __restrict__ qcount, const int* __restrict__ kcount,
                            int* __restrict__ qoff, int* __restrict__ koff)
{
  int tid = threadIdx.x;
  if (tid < 2) {
    int run = 0;
    for (int c = 0; c < NC; c++) { qoff[tid * NC + c] = run; run += qcount[tid * NC + c]; }
  } else if (tid < 4) {
    int n = tid - 2, run = 0;
    for (int c = 0; c < NC; c++) { koff[n * NC + c] = run; run += kcount[n * NC + c]; }
  }
}

__global__ void __launch_bounds__(256) scatter_kernel(
    const int* __restrict__ q_cluster, const int* __restrict__ k_cluster,
    const int* __restrict__ qoff, const int* __restrict__ koff,
    int* __restrict__ qfill, int* __restrict__ kfill,
    int* __restrict__ qlist, int* __restrict__ klist)
{
  int id = blockIdx.x * 256 + threadIdx.x;
  if (id < MROWS) {
    int row = id, n = row & 1, l = row >> 1, c = q_cluster[row];
    int pos = atomicAdd(&qfill[n * NC + c], 1);
    qlist[n * L_SEQ + qoff[n * NC + c] + pos] = l;
  } else {
    int row = id - MROWS, n = row & 1, s = row >> 1, c = k_cluster[row];
    int pos = atomicAdd(&kfill[n * NC + c], 1);
    klist[n * S_SEQ + koff[n * NC + c] + pos] = s;
  }
}

// Bucketed attention, MFMA flash-style. Block=(cluster,head,batch), 4 waves, 16 queries/wave,
// 64-key chunks with online softmax. Swapped operands keep softmax per-lane-uniform:
//   S^T = mfma(A=K, B=Q)    -> D[row=key=4g+r][col=q=lane&15]
//   O^T = mfma(A=V^T, B=P^T)-> D[row=d  =4g+r][col=q=lane&15]
// so running max / lsum / rescale are one scalar per lane (reduce = shfl_xor 16,32).
// P^T relayout through wave-private LDS: C-frag writes 4 consecutive keys (ds_write_b64),
// B-frag reads 8 consecutive keys (ds_read_b128). All LDS tiles row-XOR-swizzled
// (elem_col ^= (row&7)<<3, i.e. byte ^= (row&7)<<4) to kill the 16-way b128 bank conflict.
// Frag addressing pattern identical to gemm_bt_mfma above (harness-validated layout).
__global__ void __launch_bounds__(256) attn_bucket(
    const unsigned short* __restrict__ Qb, const unsigned short* __restrict__ Kb,
    const unsigned short* __restrict__ Vb,
    const int* __restrict__ qcount, const int* __restrict__ qoff, const int* __restrict__ qlist,
    const int* __restrict__ kcount, const int* __restrict__ koff, const int* __restrict__ klist,
    unsigned short* __restrict__ ctx)
{
  int c = blockIdx.x, h = blockIdx.y, n = blockIdx.z;
  int Sc = kcount[n * NC + c], k0base = koff[n * NC + c];
  int Lc = qcount[n * NC + c], q0 = qoff[n * NC + c];
  int tid = threadIdx.x, wave = tid >> 6, lane = tid & 63;
  int lg = lane >> 4, lq = lane & 15;

  __shared__ __align__(16) unsigned short Ks[64][64];    // [key][d], row-swizzled
  __shared__ __align__(16) unsigned short Vts[64][64];   // [d][key], row-swizzled
  __shared__ __align__(16) unsigned short Pts[4][16][64]; // per-wave [q][key], row-swizzled
  __shared__ int rb[64];                                  // gathered K/V row base offsets

  if (Sc == 0) {   // no keys: ref softmax would be NaN; R9 proved this never occurs. Write 0.
    for (int qi = wave; qi < Lc; qi += 4) {
      int l = qlist[n * L_SEQ + q0 + qi];
      ctx[((size_t)(n * L_SEQ + l)) * EMB + h * DH + lane] = 0;
    }
    return;
  }

  const int* kl = klist + n * S_SEQ + k0base;
  const int* ql = qlist + n * L_SEQ + q0;
  f32x4 zero = {0.f, 0.f, 0.f, 0.f};

  for (int qb = 0; qb < Lc; qb += 64) {           // uniform trip count across waves
    int qq = qb + wave * 16 + lq;
    int qqc = qq < Lc ? qq : Lc - 1;              // clamp: padded lanes duplicate last query
    int lrow = ql[qqc];
    const unsigned short* qp = Qb + ((size_t)(lrow * NB + n)) * EMB + h * DH;
    bf16x8 qf0 = *(const bf16x8*)(qp + lg * 8);          // B=Q frag: col=q, k=d 0..31
    bf16x8 qf1 = *(const bf16x8*)(qp + 32 + lg * 8);     //                  d 32..63

    f32x4 acc[4];                                  // O^T: 4 d-tiles, col=q per lane
#pragma unroll
    for (int di = 0; di < 4; di++) acc[di] = zero;
    float m = -3.0e38f, lsum = 0.f;

    for (int kc = 0; kc < Sc; kc += 64) {
      __syncthreads();                             // prev chunk compute done
      if (tid < 64) {
        int jj = kc + tid; if (jj >= Sc) jj = Sc - 1;   // clamp-pad: valid finite rows
        rb[tid] = (kl[jj] * NB + n) * EMB + h * DH;
      }
      __syncthreads();                             // rb ready
#pragma unroll
      for (int it = 0; it < 2; it++) {
        int p = it * 256 + tid;                    // 512 pieces
        {                                          // K: [key][d] 16B pieces
          int row = p >> 3, seg = p & 7;
          uint4 u = *(const uint4*)(Kb + rb[row] + seg * 8);
          *(uint4*)(&Ks[row][(seg * 8) ^ ((row & 7) << 3)]) = u;
        }
        {                                          // V^T: gather column d, 8 keys
          int d = p & 63, kg = p >> 6;
          unsigned short v0 = Vb[rb[kg * 8 + 0] + d], v1 = Vb[rb[kg * 8 + 1] + d];
          unsigned short v2 = Vb[rb[kg * 8 + 2] + d], v3 = Vb[rb[kg * 8 + 3] + d];
          unsigned short v4 = Vb[rb[kg * 8 + 4] + d], v5 = Vb[rb[kg * 8 + 5] + d];
          unsigned short v6 = Vb[rb[kg * 8 + 6] + d], v7 = Vb[rb[kg * 8 + 7] + d];
          uint4 u;
          u.x = (uint32_t)v0 | ((uint32_t)v1 << 16);
          u.y = (uint32_t)v2 | ((uint32_t)v3 << 16);
          u.z = (uint32_t)v4 | ((uint32_t)v5 << 16);
          u.w = (uint32_t)v6 | ((uint32_t)v7 << 16);
          *(uint4*)(&Vts[d][(kg * 8) ^ ((d & 7) << 3)]) = u;
        }
      }
      __syncthreads();                             // K/V^T staged

      // S^T = K @ Q^T : 4 key-tiles x 2 d-steps
      f32x4 st[4];
#pragma unroll
      for (int ni = 0; ni < 4; ni++) st[ni] = zero;
#pragma unroll
      for (int ni = 0; ni < 4; ni++) {
        int row = ni * 16 + lq;
        bf16x8 kf0 = *(const bf16x8*)(&Ks[row][(lg * 8) ^ ((row & 7) << 3)]);
        bf16x8 kf1 = *(const bf16x8*)(&Ks[row][(32 + lg * 8) ^ ((row & 7) << 3)]);
        st[ni] = __builtin_amdgcn_mfma_f32_16x16x32_bf16(kf0, qf0, st[ni], 0, 0, 0);
        st[ni] = __builtin_amdgcn_mfma_f32_16x16x32_bf16(kf1, qf1, st[ni], 0, 0, 0);
      }

      // online softmax (per-lane scalar state; clamp-padded keys duplicate valid
      // scores so they cannot change the max; they are zeroed in p below)
      int lim = Sc - kc;
      float cm = -3.0e38f;
#pragma unroll
      for (int ni = 0; ni < 4; ni++) {
        st[ni] = st[ni] * 0.125f;                  // 1/sqrt(64)
#pragma unroll
        for (int r = 0; r < 4; r++) cm = fmaxf(cm, st[ni][r]);
      }
      cm = fmaxf(cm, __shfl_xor(cm, 16, 64));
      cm = fmaxf(cm, __shfl_xor(cm, 32, 64));
      float mn = fmaxf(m, cm);
      float fac = __expf(m - mn);
      m = mn;
      lsum *= fac;
#pragma unroll
      for (int di = 0; di < 4; di++) acc[di] = acc[di] * fac;

      // P^T -> LDS (bf16); lsum over ROUNDED p so O stays a true weighted average
#pragma unroll
      for (int ni = 0; ni < 4; ni++) {
        int kloc = ni * 16 + lg * 4;
        float p0 = (kloc + 0 < lim) ? __expf(st[ni][0] - mn) : 0.f;
        float p1 = (kloc + 1 < lim) ? __expf(st[ni][1] - mn) : 0.f;
        float p2 = (kloc + 2 < lim) ? __expf(st[ni][2] - mn) : 0.f;
        float p3 = (kloc + 3 < lim) ? __expf(st[ni][3] - mn) : 0.f;
        unsigned short b0 = f2bf(p0), b1 = f2bf(p1), b2 = f2bf(p2), b3 = f2bf(p3);
        lsum += bf2f(b0) + bf2f(b1) + bf2f(b2) + bf2f(b3);
        ushort4 u4; u4.x = b0; u4.y = b1; u4.z = b2; u4.w = b3;
        *(ushort4*)(&Pts[wave][lq][kloc ^ ((lq & 7) << 3)]) = u4;
      }

      // O^T += V^T @ P^T : 4 d-tiles x 2 key-steps
#pragma unroll
      for (int ks = 0; ks < 2; ks++) {
        bf16x8 pf = *(const bf16x8*)(&Pts[wave][lq][(ks * 32 + lg * 8) ^ ((lq & 7) << 3)]);
#pragma unroll
        for (int di = 0; di < 4; di++) {
          int row = di * 16 + lq;
          bf16x8 vf = *(const bf16x8*)(&Vts[row][(ks * 32 + lg * 8) ^ ((row & 7) << 3)]);
          acc[di] = __builtin_amdgcn_mfma_f32_16x16x32_bf16(vf, pf, acc[di], 0, 0, 0);
        }
      }
    }

    lsum += __shfl_xor(lsum, 16, 64);
    lsum += __shfl_xor(lsum, 32, 64);
    float rinv = 1.f / lsum;
    if (qq < Lc) {                                 // padded duplicates skip the store
      unsigned short* op = ctx + ((size_t)(n * L_SEQ + lrow)) * EMB + h * DH;
#pragma unroll
      for (int di = 0; di < 4; di++) {
        ushort4 o;
        o.x = f2bf(acc[di][0] * rinv);
        o.y = f2bf(acc[di][1] * rinv);
        o.z = f2bf(acc[di][2] * rinv);
        o.w = f2bf(acc[di][3] * rinv);
        *(ushort4*)(op + di * 16 + lg * 4) = o;    // d = di*16 + 4g + r, contiguous r
      }
    }
  }
}

// Residual + LayerNorm, f32 output. out row r = l*NB+n; proj row = n*L+l. (R9-validated.)
__global__ void __launch_bounds__(256) ln_kernel(
    const float* __restrict__ proj, const float* __restrict__ query,
    const float* __restrict__ gamma, const float* __restrict__ beta,
    float* __restrict__ out)
{
  int r = blockIdx.x;
  int l = r >> 1, n = r & 1;
  int tid = threadIdx.x, wave = tid >> 6, lane = tid & 63;
  float4 p = *(const float4*)(proj + ((size_t)(n * L_SEQ + l)) * EMB + tid * 4);
  float4 qu = *(const float4*)(query + (size_t)r * EMB + tid * 4);
  float res[4] = { p.x + qu.x, p.y + qu.y, p.z + qu.z, p.w + qu.w };
  float s1 = res[0] + res[1] + res[2] + res[3];
  float s2 = res[0] * res[0] + res[1] * res[1] + res[2] * res[2] + res[3] * res[3];
#pragma unroll
  for (int off = 32; off; off >>= 1) {
    s1 += __shfl_xor(s1, off, 64);
    s2 += __shfl_xor(s2, off, 64);
  }
  __shared__ float a1[4], a2[4];
  if (lane == 0) { a1[wave] = s1; a2[wave] = s2; }
  __syncthreads();
  float t1 = a1[0] + a1[1] + a1[2] + a1[3];
  float t2 = a2[0] + a2[1] + a2[2] + a2[3];
  float mu = t1 * (1.f / EMB);
  float var = fmaxf(t2 * (1.f / EMB) - mu * mu, 0.f);
  float rstd = 1.f / sqrtf(var + 1e-5f);
  float4 gu = *(const float4*)(gamma + tid * 4);
  float4 bu = *(const float4*)(beta + tid * 4);
  float4 o;
  o.x = (res[0] - mu) * rstd * gu.x + bu.x;
  o.y = (res[1] - mu) * rstd * gu.y + bu.y;
  o.z = (res[2] - mu) * rstd * gu.z + bu.z;
  o.w = (res[3] - mu) * rstd * gu.w + bu.w;
  *(float4*)(out + (size_t)r * EMB + tid * 4) = o;
}

extern "C" void kernel_launch(void* const* d_in, const int* in_sizes, int n_in,
                              void* d_out, int out_size, void* d_ws, size_t ws_size,
                              hipStream_t stream) {
  const float* query = (const float*)d_in[0];
  const float* key   = (const float*)d_in[1];
  const float* value = (const float*)d_in[2];
  const float* Wq = (const float*)d_in[3];
  const float* bq = (const float*)d_in[4];
  const float* Wk = (const float*)d_in[5];
  const float* bk = (const float*)d_in[6];
  const float* Wv = (const float*)d_in[7];
  const float* bv = (const float*)d_in[8];
  const float* Wo = (const float*)d_in[9];
  const float* bo = (const float*)d_in[10];
  const float* cq = (const float*)d_in[11];
  const float* ck = (const float*)d_in[12];
  const float* gamma = (const float*)d_in[13];
  const float* beta  = (const float*)d_in[14];
  float* out = (float*)d_out;   // f32 output (reference dtype)

  const size_t MB_EL = (size_t)MROWS * EMB;   // 4M elements

  // workspace (~33 MB): control block first, then bf16 tensors; proj aliases Qb+Kb.
  int* q_cluster = (int*)d_ws;               // 16 KB
  int* k_cluster = q_cluster + MROWS;        // 16 KB
  int* qcount = k_cluster + MROWS;           // 6 x 64 ints contiguous (one memset)
  int* kcount = qcount + 64;
  int* qoff   = kcount + 64;
  int* koff   = qoff + 64;
  int* qfill  = koff + 64;
  int* kfill  = qfill + 64;
  int* qlist  = kfill + 64;                  // [2][2048]
  int* klist  = qlist + MROWS;               // [2][2048]
  double* Wcq = (double*)(klist + MROWS);    // 256 KB (offset 67072, 16B-aligned) [k][c] layout
  double* Wck = Wcq + (size_t)NC * EMB;      // 256 KB [k][c] layout
  double* bdq = Wck + (size_t)NC * EMB;
  double* bdk = bdq + NC;
  unsigned short* Qb  = (unsigned short*)(bdk + NC);  // 8 MB bf16, row = seq*2+n
  unsigned short* Kb  = Qb + MB_EL;                   // 8 MB
  unsigned short* Vb  = Kb + MB_EL;                   // 8 MB
  unsigned short* ctx = Vb + MB_EL;                   // 8 MB, row = n*L+l
  float* proj = (float*)Qb;    // 16 MB f32 overlays Qb+Kb (dead after attention)

  hipMemsetAsync(qcount, 0, 6 * 64 * sizeof(int), stream);

  prep_wc_kernel<<<EMB, 256, 0, stream>>>(Wq, bq, cq, Wcq, bdq);
  prep_wc_kernel<<<EMB, 256, 0, stream>>>(Wk, bk, ck, Wck, bdk);

  dim3 gg(EMB / 128, MROWS / 128);
  gemm_bt_mfma<0><<<gg, 256, 0, stream>>>(query, Wq, bq, nullptr, Qb);
  gemm_bt_mfma<0><<<gg, 256, 0, stream>>>(key,   Wk, bk, nullptr, Kb);
  gemm_bt_mfma<0><<<gg, 256, 0, stream>>>(value, Wv, bv, nullptr, Vb);

  assign2_kernel<<<dim3(MROWS / 16, 2), 256, 0, stream>>>(
      query, Wcq, bdq, q_cluster, qcount,
      key,   Wck, bdk, k_cluster, kcount);

  scan_kernel<<<1, 64, 0, stream>>>(qcount, kcount, qoff, koff);
  scatter_kernel<<<(2 * MROWS) / 256, 256, 0, stream>>>(q_cluster, k_cluster, qoff, koff,
                                                        qfill, kfill, qlist, klist);
  attn_bucket<<<dim3(NC, NH, NB), 256, 0, stream>>>(Qb, Kb, Vb, qcount, qoff, qlist,
                                                    kcount, koff, klist, ctx);
  gemm_bt_mfma<1><<<gg, 256, 0, stream>>>(ctx, Wo, bo, proj, nullptr);
  ln_kernel<<<MROWS, 256, 0, stream>>>(proj, query, gamma, beta, out);
}

// Round 5
// 408.071 us; speedup vs baseline: 1.3418x; 1.1257x over previous
//
#include <hip/hip_runtime.h>
#include <stdint.h>

#define L_SEQ 2048
#define S_SEQ 2048
#define NB 2
#define EMB 1024
#define NH 16
#define DH 64
#define NC 32
#define MROWS 4096  // L*N

typedef __bf16 bf16x8 __attribute__((ext_vector_type(8)));
typedef float f32x4 __attribute__((ext_vector_type(4)));

__device__ __forceinline__ float bf2f(unsigned short u) {
  return __builtin_bit_cast(float, (uint32_t)u << 16);
}
__device__ __forceinline__ unsigned short f2bf(float f) {
  uint32_t u = __builtin_bit_cast(uint32_t, f);
  return (unsigned short)((u + 0x7FFFu + ((u >> 16) & 1u)) >> 16);
}

// Async global->LDS staging (m97 lever). LDS dest is wave-uniform base + lane*16 in our
// staging pattern (consecutive tid -> consecutive 16B LDS chunks), which is the documented
// contract. Fallback: plain vector copy (same data, VGPR round-trip).
#if defined(__has_builtin) && __has_builtin(__builtin_amdgcn_global_load_lds)
#define GLOAD_LDS(gp, lp)                                            \
  __builtin_amdgcn_global_load_lds(                                  \
      (const __attribute__((address_space(1))) void*)(gp),           \
      (__attribute__((address_space(3))) void*)(lp), 16, 0, 0)
#else
#define GLOAD_LDS(gp, lp) do { *(uint4*)(lp) = *(const uint4*)(gp); } while (0)
#endif

// f32 -> bf16 RNE convert, 8 elems/thread, vectorized. Same f2bf as the GEMM previously
// applied inline, so GEMM inputs are bit-identical to the validated inline-convert path.
__global__ void __launch_bounds__(256) conv_f2bf_kernel(
    const float* __restrict__ src, unsigned short* __restrict__ dst, int n8)
{
  int id = blockIdx.x * 256 + threadIdx.x;
  if (id >= n8) return;
  const float4* s = (const float4*)src + (size_t)id * 2;
  float4 a0 = s[0], a1 = s[1];
  uint4 u;
  u.x = (uint32_t)f2bf(a0.x) | ((uint32_t)f2bf(a0.y) << 16);
  u.y = (uint32_t)f2bf(a0.z) | ((uint32_t)f2bf(a0.w) << 16);
  u.z = (uint32_t)f2bf(a1.x) | ((uint32_t)f2bf(a1.y) << 16);
  u.w = (uint32_t)f2bf(a1.z) | ((uint32_t)f2bf(a1.w) << 16);
  ((uint4*)dst)[id] = u;
}

// C = A @ B^T + bias. MFMA bf16, 128x128 tile (m93/m97-validated frag/epilogue structure).
// Both operands bf16 (pre-converted) -> staging is pure global_load_lds width-16
// (4 calls/thread/K-step), no VALU conversion in the loop. Out: f32 if outF, else bf16.
__global__ void __launch_bounds__(256) gemm_bt_mfma(
    const unsigned short* __restrict__ A, const unsigned short* __restrict__ B,
    const float* __restrict__ bias,
    float* __restrict__ outF, unsigned short* __restrict__ outB)
{
  __shared__ __align__(16) unsigned short As[128][32];  // unpadded 64B rows (b128-aligned)
  __shared__ __align__(16) unsigned short Bs[128][32];
  const int K = EMB;
  int tid = threadIdx.x;
  int m0 = blockIdx.y * 128, n0 = blockIdx.x * 128;
  int wave = tid >> 6, lane = tid & 63;
  int wm = (wave >> 1) * 64, wn = (wave & 1) * 64;

  f32x4 zero = {0.f, 0.f, 0.f, 0.f};
  f32x4 acc[4][4];
#pragma unroll
  for (int mi = 0; mi < 4; mi++)
#pragma unroll
    for (int ni = 0; ni < 4; ni++) acc[mi][ni] = zero;

  int fr = lane & 15, fk = (lane >> 4) * 8;

  for (int k0 = 0; k0 < K; k0 += 32) {
    __syncthreads();
#pragma unroll
    for (int it = 0; it < 2; it++) {
      int ch = tid + it * 256;          // 512 chunks of 8 bf16 per tile
      int row = ch >> 2, kk = (ch & 3) * 8;
      GLOAD_LDS(A + (size_t)(m0 + row) * K + k0 + kk, &As[row][kk]);
      GLOAD_LDS(B + (size_t)(n0 + row) * K + k0 + kk, &Bs[row][kk]);
    }
    __syncthreads();
    bf16x8 af[4], bfr[4];
#pragma unroll
    for (int i = 0; i < 4; i++) af[i] = *(const bf16x8*)(&As[wm + i * 16 + fr][fk]);
#pragma unroll
    for (int i = 0; i < 4; i++) bfr[i] = *(const bf16x8*)(&Bs[wn + i * 16 + fr][fk]);
#pragma unroll
    for (int mi = 0; mi < 4; mi++)
#pragma unroll
      for (int ni = 0; ni < 4; ni++)
        acc[mi][ni] = __builtin_amdgcn_mfma_f32_16x16x32_bf16(af[mi], bfr[ni], acc[mi][ni], 0, 0, 0);
  }

#pragma unroll
  for (int ni = 0; ni < 4; ni++) {
    int col = n0 + wn + ni * 16 + (lane & 15);
    float bv = bias[col];
#pragma unroll
    for (int mi = 0; mi < 4; mi++) {
#pragma unroll
      for (int r = 0; r < 4; r++) {
        int row = m0 + wm + mi * 16 + (lane >> 4) * 4 + r;
        float v = acc[mi][ni][r] + bv;
        if (outF) outF[(size_t)row * EMB + col] = v;
        else outB[(size_t)row * EMB + col] = f2bf(v);
      }
    }
  }
}

// WcT[k][c] = sum_e W[e][k]*cent[c][e]; bd[c] = sum_e bias[e]*cent[c][e]; f64 (exact reassociation:
// (x@W^T+b)·cent_c = sum_k x_k*WcT[k][c] + bd[c]). Inputs f32. [k][c] layout: coalesced for the
// assignment LDS staging.
__global__ void __launch_bounds__(256) prep_wc_kernel(
    const float* __restrict__ W, const float* __restrict__ bias,
    const float* __restrict__ cent,
    double* __restrict__ WcT, double* __restrict__ bd)
{
  int k = blockIdx.x;
  int tid = threadIdx.x;
  int c = tid & 31, g = tid >> 5;
  __shared__ double red[8][32];
  double s = 0.0;
  for (int e = g * 128; e < (g + 1) * 128; e++)
    s += (double)W[(size_t)e * EMB + k] * (double)cent[(size_t)c * EMB + e];
  red[g][c] = s;
  __syncthreads();
  if (tid < 32) {
    double t = 0.0;
#pragma unroll
    for (int gg = 0; gg < 8; gg++) t += red[gg][tid];
    WcT[(size_t)k * NC + tid] = t;
  }
  if (k == 0) {
    __syncthreads();
    double s2 = 0.0;
    for (int e = g * 128; e < (g + 1) * 128; e++)
      s2 += (double)bias[e] * (double)cent[(size_t)c * EMB + e];
    red[g][c] = s2;
    __syncthreads();
    if (tid < 32) {
      double t = 0.0;
#pragma unroll
      for (int gg = 0; gg < 8; gg++) t += red[gg][tid];
      bd[tid] = t;
    }
  }
}

// Assignment from RAW f32 input rows via WcT: f64 dots, first-max argmax.
// R3-validated version (63.8us). LDS-tiled: block = 16 rows x 32 clusters; per 64-k chunk,
// stage WcT chunk (16 KB, natural [k][c] layout) + X rows as f64 (8 KB) in LDS; inner loop
// LDS-resident. (R4's f64-MFMA rewrite FAILED: unverified f64 fragment layout — reverted.)
__global__ void __launch_bounds__(256, 2) assign2_kernel(
    const float* __restrict__ Xq, const double* __restrict__ WcTq, const double* __restrict__ bdq,
    int* __restrict__ qcl, int* __restrict__ qcnt,
    const float* __restrict__ Xk, const double* __restrict__ WcTk, const double* __restrict__ bdk,
    int* __restrict__ kcl, int* __restrict__ kcnt)
{
  const float* X; const double* WcT; const double* bd; int* cluster; int* count;
  if (blockIdx.y == 0) { X = Xq; WcT = WcTq; bd = bdq; cluster = qcl; count = qcnt; }
  else                 { X = Xk; WcT = WcTk; bd = bdk; cluster = kcl; count = kcnt; }

  int r0 = blockIdx.x * 16;
  int tid = threadIdx.x;
  int c = tid & 31, g = tid >> 5;

  __shared__ __align__(16) double Ws[64][32];   // [kk][c], 16 KB
  __shared__ __align__(16) double Xd[16][64];   // [row][kk], 8 KB

  double aAe = 0, aAo = 0, aBe = 0, aBo = 0;    // 2 rows x (even,odd) chains

  for (int k0 = 0; k0 < EMB; k0 += 64) {
    __syncthreads();                             // prev chunk compute done
    // stage WcT chunk: 2048 doubles, 8/thread, fully coalesced (512 B / wave-instr)
#pragma unroll
    for (int it = 0; it < 8; it++) {
      int idx = it * 256 + tid;
      ((double*)Ws)[idx] = WcT[(size_t)k0 * NC + idx];
    }
    // stage X chunk as f64: 1024 floats, float2/thread x2, coalesced
#pragma unroll
    for (int it = 0; it < 2; it++) {
      int idx = it * 256 + tid;
      int r = idx >> 5, kp = idx & 31;
      float2 xv = *(const float2*)(X + (size_t)(r0 + r) * EMB + k0 + kp * 2);
      double2 xd; xd.x = (double)xv.x; xd.y = (double)xv.y;
      *(double2*)(&Xd[r][kp * 2]) = xd;
    }
    __syncthreads();                             // tiles ready
#pragma unroll
    for (int kk = 0; kk < 64; kk += 2) {
      double w0 = Ws[kk][c], w1 = Ws[kk + 1][c];
      double2 xa = *(const double2*)(&Xd[g * 2][kk]);
      double2 xb = *(const double2*)(&Xd[g * 2 + 1][kk]);
      aAe += xa.x * w0; aAo += xa.y * w1;
      aBe += xb.x * w0; aBo += xb.y * w1;
    }
  }

  double dA = (aAe + aAo) + bd[c];
  double dB = (aBe + aBo) + bd[c];

  // argmax over c within each 32-lane half, both rows (first-max: lowest index wins ties)
  double bvA = dA; int biA = c;
  double bvB = dB; int biB = c;
#pragma unroll
  for (int off = 1; off < 32; off <<= 1) {
    double ovA = __shfl_xor(bvA, off, 64); int oiA = __shfl_xor(biA, off, 64);
    if (ovA > bvA || (ovA == bvA && oiA < biA)) { bvA = ovA; biA = oiA; }
    double ovB = __shfl_xor(bvB, off, 64); int oiB = __shfl_xor(biB, off, 64);
    if (ovB > bvB || (ovB == bvB && oiB < biB)) { bvB = ovB; biB = oiB; }
  }
  if (c == 0) {
    int rowA = r0 + g * 2, rowB = rowA + 1;
    cluster[rowA] = biA; atomicAdd(&count[(rowA & 1) * NC + biA], 1);
    cluster[rowB] = biB; atomicAdd(&count[(rowB & 1) * NC + biB], 1);
  }
}

__global__ void scan_kernel(const int* __restrict__ qcount, const int* __restrict__ kcount,
                            int* __restrict__ qoff, int* __restrict__ koff)
{
  int tid = threadIdx.x;
  if (tid < 2) {
    int run = 0;
    for (int c = 0; c < NC; c++) { qoff[tid * NC + c] = run; run += qcount[tid * NC + c]; }
  } else if (tid < 4) {
    int n = tid - 2, run = 0;
    for (int c = 0; c < NC; c++) { koff[n * NC + c] = run; run += kcount[n * NC + c]; }
  }
}

__global__ void __launch_bounds__(256) scatter_kernel(
    const int* __restrict__ q_cluster, const int* __restrict__ k_cluster,
    const int* __restrict__ qoff, const int* __restrict__ koff,
    int* __restrict__ qfill, int* __restrict__ kfill,
    int* __restrict__ qlist, int* __restrict__ klist)
{
  int id = blockIdx.x * 256 + threadIdx.x;
  if (id < MROWS) {
    int row = id, n = row & 1, l = row >> 1, c = q_cluster[row];
    int pos = atomicAdd(&qfill[n * NC + c], 1);
    qlist[n * L_SEQ + qoff[n * NC + c] + pos] = l;
  } else {
    int row = id - MROWS, n = row & 1, s = row >> 1, c = k_cluster[row];
    int pos = atomicAdd(&kfill[n * NC + c], 1);
    klist[n * S_SEQ + koff[n * NC + c] + pos] = s;
  }
}

// Bucketed attention, MFMA flash-style. Block=(cluster,head,batch), 4 waves, 16 queries/wave,
// 64-key chunks with online softmax. Swapped operands keep softmax per-lane-uniform:
//   S^T = mfma(A=K, B=Q)    -> D[row=key=4g+r][col=q=lane&15]
//   O^T = mfma(A=V^T, B=P^T)-> D[row=d  =4g+r][col=q=lane&15]
// so running max / lsum / rescale are one scalar per lane (reduce = shfl_xor 16,32).
// P^T relayout through wave-private LDS; all LDS tiles row-XOR-swizzled. (R1-validated.)
__global__ void __launch_bounds__(256) attn_bucket(
    const unsigned short* __restrict__ Qb, const unsigned short* __restrict__ Kb,
    const unsigned short* __restrict__ Vb,
    const int* __restrict__ qcount, const int* __restrict__ qoff, const int* __restrict__ qlist,
    const int* __restrict__ kcount, const int* __restrict__ koff, const int* __restrict__ klist,
    unsigned short* __restrict__ ctx)
{
  int c = blockIdx.x, h = blockIdx.y, n = blockIdx.z;
  int Sc = kcount[n * NC + c], k0base = koff[n * NC + c];
  int Lc = qcount[n * NC + c], q0 = qoff[n * NC + c];
  int tid = threadIdx.x, wave = tid >> 6, lane = tid & 63;
  int lg = lane >> 4, lq = lane & 15;

  __shared__ __align__(16) unsigned short Ks[64][64];    // [key][d], row-swizzled
  __shared__ __align__(16) unsigned short Vts[64][64];   // [d][key], row-swizzled
  __shared__ __align__(16) unsigned short Pts[4][16][64]; // per-wave [q][key], row-swizzled
  __shared__ int rb[64];                                  // gathered K/V row base offsets

  if (Sc == 0) {   // no keys: ref softmax would be NaN; R9 proved this never occurs. Write 0.
    for (int qi = wave; qi < Lc; qi += 4) {
      int l = qlist[n * L_SEQ + q0 + qi];
      ctx[((size_t)(n * L_SEQ + l)) * EMB + h * DH + lane] = 0;
    }
    return;
  }

  const int* kl = klist + n * S_SEQ + k0base;
  const int* ql = qlist + n * L_SEQ + q0;
  f32x4 zero = {0.f, 0.f, 0.f, 0.f};

  for (int qb = 0; qb < Lc; qb += 64) {           // uniform trip count across waves
    int qq = qb + wave * 16 + lq;
    int qqc = qq < Lc ? qq : Lc - 1;              // clamp: padded lanes duplicate last query
    int lrow = ql[qqc];
    const unsigned short* qp = Qb + ((size_t)(lrow * NB + n)) * EMB + h * DH;
    bf16x8 qf0 = *(const bf16x8*)(qp + lg * 8);          // B=Q frag: col=q, k=d 0..31
    bf16x8 qf1 = *(const bf16x8*)(qp + 32 + lg * 8);     //                  d 32..63

    f32x4 acc[4];                                  // O^T: 4 d-tiles, col=q per lane
#pragma unroll
    for (int di = 0; di < 4; di++) acc[di] = zero;
    float m = -3.0e38f, lsum = 0.f;

    for (int kc = 0; kc < Sc; kc += 64) {
      __syncthreads();                             // prev chunk compute done
      if (tid < 64) {
        int jj = kc + tid; if (jj >= Sc) jj = Sc - 1;   // clamp-pad: valid finite rows
        rb[tid] = (kl[jj] * NB + n) * EMB + h * DH;
      }
      __syncthreads();                             // rb ready
#pragma unroll
      for (int it = 0; it < 2; it++) {
        int p = it * 256 + tid;                    // 512 pieces
        {                                          // K: [key][d] 16B pieces
          int row = p >> 3, seg = p & 7;
          uint4 u = *(const uint4*)(Kb + rb[row] + seg * 8);
          *(uint4*)(&Ks[row][(seg * 8) ^ ((row & 7) << 3)]) = u;
        }
        {                                          // V^T: gather column d, 8 keys
          int d = p & 63, kg = p >> 6;
          unsigned short v0 = Vb[rb[kg * 8 + 0] + d], v1 = Vb[rb[kg * 8 + 1] + d];
          unsigned short v2 = Vb[rb[kg * 8 + 2] + d], v3 = Vb[rb[kg * 8 + 3] + d];
          unsigned short v4 = Vb[rb[kg * 8 + 4] + d], v5 = Vb[rb[kg * 8 + 5] + d];
          unsigned short v6 = Vb[rb[kg * 8 + 6] + d], v7 = Vb[rb[kg * 8 + 7] + d];
          uint4 u;
          u.x = (uint32_t)v0 | ((uint32_t)v1 << 16);
          u.y = (uint32_t)v2 | ((uint32_t)v3 << 16);
          u.z = (uint32_t)v4 | ((uint32_t)v5 << 16);
          u.w = (uint32_t)v6 | ((uint32_t)v7 << 16);
          *(uint4*)(&Vts[d][(kg * 8) ^ ((d & 7) << 3)]) = u;
        }
      }
      __syncthreads();                             // K/V^T staged

      // S^T = K @ Q^T : 4 key-tiles x 2 d-steps
      f32x4 st[4];
#pragma unroll
      for (int ni = 0; ni < 4; ni++) st[ni] = zero;
#pragma unroll
      for (int ni = 0; ni < 4; ni++) {
        int row = ni * 16 + lq;
        bf16x8 kf0 = *(const bf16x8*)(&Ks[row][(lg * 8) ^ ((row & 7) << 3)]);
        bf16x8 kf1 = *(const bf16x8*)(&Ks[row][(32 + lg * 8) ^ ((row & 7) << 3)]);
        st[ni] = __builtin_amdgcn_mfma_f32_16x16x32_bf16(kf0, qf0, st[ni], 0, 0, 0);
        st[ni] = __builtin_amdgcn_mfma_f32_16x16x32_bf16(kf1, qf1, st[ni], 0, 0, 0);
      }

      // online softmax (per-lane scalar state; clamp-padded keys duplicate valid
      // scores so they cannot change the max; they are zeroed in p below)
      int lim = Sc - kc;
      float cm = -3.0e38f;
#pragma unroll
      for (int ni = 0; ni < 4; ni++) {
        st[ni] = st[ni] * 0.125f;                  // 1/sqrt(64)
#pragma unroll
        for (int r = 0; r < 4; r++) cm = fmaxf(cm, st[ni][r]);
      }
      cm = fmaxf(cm, __shfl_xor(cm, 16, 64));
      cm = fmaxf(cm, __shfl_xor(cm, 32, 64));
      float mn = fmaxf(m, cm);
      float fac = __expf(m - mn);
      m = mn;
      lsum *= fac;
#pragma unroll
      for (int di = 0; di < 4; di++) acc[di] = acc[di] * fac;

      // P^T -> LDS (bf16); lsum over ROUNDED p so O stays a true weighted average
#pragma unroll
      for (int ni = 0; ni < 4; ni++) {
        int kloc = ni * 16 + lg * 4;
        float p0 = (kloc + 0 < lim) ? __expf(st[ni][0] - mn) : 0.f;
        float p1 = (kloc + 1 < lim) ? __expf(st[ni][1] - mn) : 0.f;
        float p2 = (kloc + 2 < lim) ? __expf(st[ni][2] - mn) : 0.f;
        float p3 = (kloc + 3 < lim) ? __expf(st[ni][3] - mn) : 0.f;
        unsigned short b0 = f2bf(p0), b1 = f2bf(p1), b2 = f2bf(p2), b3 = f2bf(p3);
        lsum += bf2f(b0) + bf2f(b1) + bf2f(b2) + bf2f(b3);
        ushort4 u4; u4.x = b0; u4.y = b1; u4.z = b2; u4.w = b3;
        *(ushort4*)(&Pts[wave][lq][kloc ^ ((lq & 7) << 3)]) = u4;
      }

      // O^T += V^T @ P^T : 4 d-tiles x 2 key-steps
#pragma unroll
      for (int ks = 0; ks < 2; ks++) {
        bf16x8 pf = *(const bf16x8*)(&Pts[wave][lq][(ks * 32 + lg * 8) ^ ((lq & 7) << 3)]);
#pragma unroll
        for (int di = 0; di < 4; di++) {
          int row = di * 16 + lq;
          bf16x8 vf = *(const bf16x8*)(&Vts[row][(ks * 32 + lg * 8) ^ ((row & 7) << 3)]);
          acc[di] = __builtin_amdgcn_mfma_f32_16x16x32_bf16(vf, pf, acc[di], 0, 0, 0);
        }
      }
    }

    lsum += __shfl_xor(lsum, 16, 64);
    lsum += __shfl_xor(lsum, 32, 64);
    float rinv = 1.f / lsum;
    if (qq < Lc) {                                 // padded duplicates skip the store
      unsigned short* op = ctx + ((size_t)(n * L_SEQ + lrow)) * EMB + h * DH;
#pragma unroll
      for (int di = 0; di < 4; di++) {
        ushort4 o;
        o.x = f2bf(acc[di][0] * rinv);
        o.y = f2bf(acc[di][1] * rinv);
        o.z = f2bf(acc[di][2] * rinv);
        o.w = f2bf(acc[di][3] * rinv);
        *(ushort4*)(op + di * 16 + lg * 4) = o;    // d = di*16 + 4g + r, contiguous r
      }
    }
  }
}

// Residual + LayerNorm, f32 output. out row r = l*NB+n; proj row = n*L+l. (R9-validated.)
__global__ void __launch_bounds__(256) ln_kernel(
    const float* __restrict__ proj, const float* __restrict__ query,
    const float* __restrict__ gamma, const float* __restrict__ beta,
    float* __restrict__ out)
{
  int r = blockIdx.x;
  int l = r >> 1, n = r & 1;
  int tid = threadIdx.x, wave = tid >> 6, lane = tid & 63;
  float4 p = *(const float4*)(proj + ((size_t)(n * L_SEQ + l)) * EMB + tid * 4);
  float4 qu = *(const float4*)(query + (size_t)r * EMB + tid * 4);
  float res[4] = { p.x + qu.x, p.y + qu.y, p.z + qu.z, p.w + qu.w };
  float s1 = res[0] + res[1] + res[2] + res[3];
  float s2 = res[0] * res[0] + res[1] * res[1] + res[2] * res[2] + res[3] * res[3];
#pragma unroll
  for (int off = 32; off; off >>= 1) {
    s1 += __shfl_xor(s1, off, 64);
    s2 += __shfl_xor(s2, off, 64);
  }
  __shared__ float a1[4], a2[4];
  if (lane == 0) { a1[wave] = s1; a2[wave] = s2; }
  __syncthreads();
  float t1 = a1[0] + a1[1] + a1[2] + a1[3];
  float t2 = a2[0] + a2[1] + a2[2] + a2[3];
  float mu = t1 * (1.f / EMB);
  float var = fmaxf(t2 * (1.f / EMB) - mu * mu, 0.f);
  float rstd = 1.f / sqrtf(var + 1e-5f);
  float4 gu = *(const float4*)(gamma + tid * 4);
  float4 bu = *(const float4*)(beta + tid * 4);
  float4 o;
  o.x = (res[0] - mu) * rstd * gu.x + bu.x;
  o.y = (res[1] - mu) * rstd * gu.y + bu.y;
  o.z = (res[2] - mu) * rstd * gu.z + bu.z;
  o.w = (res[3] - mu) * rstd * gu.w + bu.w;
  *(float4*)(out + (size_t)r * EMB + tid * 4) = o;
}

extern "C" void kernel_launch(void* const* d_in, const int* in_sizes, int n_in,
                              void* d_out, int out_size, void* d_ws, size_t ws_size,
                              hipStream_t stream) {
  const float* query = (const float*)d_in[0];
  const float* key   = (const float*)d_in[1];
  const float* value = (const float*)d_in[2];
  const float* Wq = (const float*)d_in[3];
  const float* bq = (const float*)d_in[4];
  const float* Wk = (const float*)d_in[5];
  const float* bk = (const float*)d_in[6];
  const float* Wv = (const float*)d_in[7];
  const float* bv = (const float*)d_in[8];
  const float* Wo = (const float*)d_in[9];
  const float* bo = (const float*)d_in[10];
  const float* cq = (const float*)d_in[11];
  const float* ck = (const float*)d_in[12];
  const float* gamma = (const float*)d_in[13];
  const float* beta  = (const float*)d_in[14];
  float* out = (float*)d_out;   // f32 output (reference dtype)

  const size_t MB_EL = (size_t)MROWS * EMB;   // 4M elements

  // workspace (~35 MB): control block first, then bf16 tensors; proj aliases Qb+Kb;
  // xbf (bf16 input scratch) aliases ctx (dead until attention); wbf appended (2 MB).
  int* q_cluster = (int*)d_ws;               // 16 KB
  int* k_cluster = q_cluster + MROWS;        // 16 KB
  int* qcount = k_cluster + MROWS;           // 6 x 64 ints contiguous (one memset)
  int* kcount = qcount + 64;
  int* qoff   = kcount + 64;
  int* koff   = qoff + 64;
  int* qfill  = koff + 64;
  int* kfill  = qfill + 64;
  int* qlist  = kfill + 64;                  // [2][2048]
  int* klist  = qlist + MROWS;               // [2][2048]
  double* Wcq = (double*)(klist + MROWS);    // 256 KB (offset 67072, 16B-aligned) [k][c] layout
  double* Wck = Wcq + (size_t)NC * EMB;      // 256 KB [k][c] layout
  double* bdq = Wck + (size_t)NC * EMB;
  double* bdk = bdq + NC;
  unsigned short* Qb  = (unsigned short*)(bdk + NC);  // 8 MB bf16, row = seq*2+n
  unsigned short* Kb  = Qb + MB_EL;                   // 8 MB
  unsigned short* Vb  = Kb + MB_EL;                   // 8 MB
  unsigned short* ctx = Vb + MB_EL;                   // 8 MB, row = n*L+l
  unsigned short* wbf = ctx + MB_EL;                  // 2 MB bf16 weight scratch (reused 4x)
  unsigned short* xbf = ctx;   // bf16 input scratch overlays ctx (dead until attn writes it)
  float* proj = (float*)Qb;    // 16 MB f32 overlays Qb+Kb (dead after attention)

  const int W8 = (EMB * EMB) / 8;     // 131072 -> 512 blocks
  const int X8 = (int)(MB_EL / 8);    // 524288 -> 2048 blocks

  hipMemsetAsync(qcount, 0, 6 * 64 * sizeof(int), stream);

  prep_wc_kernel<<<EMB, 256, 0, stream>>>(Wq, bq, cq, Wcq, bdq);
  prep_wc_kernel<<<EMB, 256, 0, stream>>>(Wk, bk, ck, Wck, bdk);

  dim3 gg(EMB / 128, MROWS / 128);
  conv_f2bf_kernel<<<W8 / 256, 256, 0, stream>>>(Wq, wbf, W8);
  conv_f2bf_kernel<<<X8 / 256, 256, 0, stream>>>(query, xbf, X8);
  gemm_bt_mfma<<<gg, 256, 0, stream>>>(xbf, wbf, bq, nullptr, Qb);

  conv_f2bf_kernel<<<W8 / 256, 256, 0, stream>>>(Wk, wbf, W8);
  conv_f2bf_kernel<<<X8 / 256, 256, 0, stream>>>(key, xbf, X8);
  gemm_bt_mfma<<<gg, 256, 0, stream>>>(xbf, wbf, bk, nullptr, Kb);

  conv_f2bf_kernel<<<W8 / 256, 256, 0, stream>>>(Wv, wbf, W8);
  conv_f2bf_kernel<<<X8 / 256, 256, 0, stream>>>(value, xbf, X8);
  gemm_bt_mfma<<<gg, 256, 0, stream>>>(xbf, wbf, bv, nullptr, Vb);

  assign2_kernel<<<dim3(MROWS / 16, 2), 256, 0, stream>>>(
      query, Wcq, bdq, q_cluster, qcount,
      key,   Wck, bdk, k_cluster, kcount);

  scan_kernel<<<1, 64, 0, stream>>>(qcount, kcount, qoff, koff);
  scatter_kernel<<<(2 * MROWS) / 256, 256, 0, stream>>>(q_cluster, k_cluster, qoff, koff,
                                                        qfill, kfill, qlist, klist);
  attn_bucket<<<dim3(NC, NH, NB), 256, 0, stream>>>(Qb, Kb, Vb, qcount, qoff, qlist,
                                                    kcount, koff, klist, ctx);

  conv_f2bf_kernel<<<W8 / 256, 256, 0, stream>>>(Wo, wbf, W8);
  gemm_bt_mfma<<<gg, 256, 0, stream>>>(ctx, wbf, bo, proj, nullptr);
  ln_kernel<<<MROWS, 256, 0, stream>>>(proj, query, gamma, beta, out);
}

// Round 7
// 369.849 us; speedup vs baseline: 1.4805x; 1.1033x over previous
//
#include <hip/hip_runtime.h>
#include <stdint.h>

#define L_SEQ 2048
#define S_SEQ 2048
#define NB 2
#define EMB 1024
#define NH 16
#define DH 64
#define NC 32
#define MROWS 4096  // L*N

typedef __bf16 bf16x8 __attribute__((ext_vector_type(8)));
typedef float f32x4 __attribute__((ext_vector_type(4)));

__device__ __forceinline__ float bf2f(unsigned short u) {
  return __builtin_bit_cast(float, (uint32_t)u << 16);
}
__device__ __forceinline__ unsigned short f2bf(float f) {
  uint32_t u = __builtin_bit_cast(uint32_t, f);
  return (unsigned short)((u + 0x7FFFu + ((u >> 16) & 1u)) >> 16);
}

// Async global->LDS staging (m97 lever). LDS dest is wave-uniform base + lane*16 in our
// staging pattern (consecutive tid -> consecutive 16B LDS chunks), which is the documented
// contract. Fallback: plain vector copy (same data, VGPR round-trip).
#if defined(__has_builtin) && __has_builtin(__builtin_amdgcn_global_load_lds)
#define GLOAD_LDS(gp, lp)                                            \
  __builtin_amdgcn_global_load_lds(                                  \
      (const __attribute__((address_space(1))) void*)(gp),           \
      (__attribute__((address_space(3))) void*)(lp), 16, 0, 0)
#else
#define GLOAD_LDS(gp, lp) do { *(uint4*)(lp) = *(const uint4*)(gp); } while (0)
#endif

// f32 -> bf16 RNE convert, 8 elems/thread, vectorized. Same f2bf as the GEMM previously
// applied inline, so GEMM inputs are bit-identical to the validated inline-convert path.
__global__ void __launch_bounds__(256) conv_f2bf_kernel(
    const float* __restrict__ src, unsigned short* __restrict__ dst, int n8)
{
  int id = blockIdx.x * 256 + threadIdx.x;
  if (id >= n8) return;
  const float4* s = (const float4*)src + (size_t)id * 2;
  float4 a0 = s[0], a1 = s[1];
  uint4 u;
  u.x = (uint32_t)f2bf(a0.x) | ((uint32_t)f2bf(a0.y) << 16);
  u.y = (uint32_t)f2bf(a0.z) | ((uint32_t)f2bf(a0.w) << 16);
  u.z = (uint32_t)f2bf(a1.x) | ((uint32_t)f2bf(a1.y) << 16);
  u.w = (uint32_t)f2bf(a1.z) | ((uint32_t)f2bf(a1.w) << 16);
  ((uint4*)dst)[id] = u;
}

// C = A @ B^T + bias. MFMA bf16, 128x128 tile (m93/m97-validated frag/epilogue structure).
// Both operands bf16 (pre-converted) -> staging is pure global_load_lds width-16
// (4 calls/thread/K-step), no VALU conversion in the loop. Out: f32 if outF, else bf16.
__global__ void __launch_bounds__(256) gemm_bt_mfma(
    const unsigned short* __restrict__ A, const unsigned short* __restrict__ B,
    const float* __restrict__ bias,
    float* __restrict__ outF, unsigned short* __restrict__ outB)
{
  __shared__ __align__(16) unsigned short As[128][32];  // unpadded 64B rows (b128-aligned)
  __shared__ __align__(16) unsigned short Bs[128][32];
  const int K = EMB;
  int tid = threadIdx.x;
  int m0 = blockIdx.y * 128, n0 = blockIdx.x * 128;
  int wave = tid >> 6, lane = tid & 63;
  int wm = (wave >> 1) * 64, wn = (wave & 1) * 64;

  f32x4 zero = {0.f, 0.f, 0.f, 0.f};
  f32x4 acc[4][4];
#pragma unroll
  for (int mi = 0; mi < 4; mi++)
#pragma unroll
    for (int ni = 0; ni < 4; ni++) acc[mi][ni] = zero;

  int fr = lane & 15, fk = (lane >> 4) * 8;

  for (int k0 = 0; k0 < K; k0 += 32) {
    __syncthreads();
#pragma unroll
    for (int it = 0; it < 2; it++) {
      int ch = tid + it * 256;          // 512 chunks of 8 bf16 per tile
      int row = ch >> 2, kk = (ch & 3) * 8;
      GLOAD_LDS(A + (size_t)(m0 + row) * K + k0 + kk, &As[row][kk]);
      GLOAD_LDS(B + (size_t)(n0 + row) * K + k0 + kk, &Bs[row][kk]);
    }
    __syncthreads();
    bf16x8 af[4], bfr[4];
#pragma unroll
    for (int i = 0; i < 4; i++) af[i] = *(const bf16x8*)(&As[wm + i * 16 + fr][fk]);
#pragma unroll
    for (int i = 0; i < 4; i++) bfr[i] = *(const bf16x8*)(&Bs[wn + i * 16 + fr][fk]);
#pragma unroll
    for (int mi = 0; mi < 4; mi++)
#pragma unroll
      for (int ni = 0; ni < 4; ni++)
        acc[mi][ni] = __builtin_amdgcn_mfma_f32_16x16x32_bf16(af[mi], bfr[ni], acc[mi][ni], 0, 0, 0);
  }

#pragma unroll
  for (int ni = 0; ni < 4; ni++) {
    int col = n0 + wn + ni * 16 + (lane & 15);
    float bv = bias[col];
#pragma unroll
    for (int mi = 0; mi < 4; mi++) {
#pragma unroll
      for (int r = 0; r < 4; r++) {
        int row = m0 + wm + mi * 16 + (lane >> 4) * 4 + r;
        float v = acc[mi][ni][r] + bv;
        if (outF) outF[(size_t)row * EMB + col] = v;
        else outB[(size_t)row * EMB + col] = f2bf(v);
      }
    }
  }
}

// prep stage 1: partial[es][c][k] = sum_{e in es-chunk, ascending} W[e][k]*cent[c][e], f64.
// R5 theory: old prep_wc (block-per-k, W column walks + 128KB cent re-stream per block,
// ~50-65us each by budget elimination) was scatter-bound. New structure: W reads coalesced
// 256B row-runs; cent rows are WAVE-UNIFORM (cbase via readfirstlane -> provably uniform ->
// scalar-pipe s_load, zero VMEM cost); inner loop = 8 independent f64 FMA chains.
// grid (16 e-splits, 16 k-tiles, 2 matrices), block 256 = 4 waves x 8 cent-rows.
__global__ void __launch_bounds__(256) prep_partial_kernel(
    const float* __restrict__ Wq_, const float* __restrict__ cq_,
    const float* __restrict__ Wk_, const float* __restrict__ ck_,
    double* __restrict__ partQ, double* __restrict__ partK)
{
  const float* W; const float* cent; double* part;
  if (blockIdx.z == 0) { W = Wq_; cent = cq_; part = partQ; }
  else                 { W = Wk_; cent = ck_; part = partK; }
  int tid = threadIdx.x;
  int k = (blockIdx.y << 6) | (tid & 63);
  int cbase = __builtin_amdgcn_readfirstlane(tid >> 6) * 8;   // wave-uniform -> s_load path
  int e0 = blockIdx.x << 6;

  double acc[8];
#pragma unroll
  for (int j = 0; j < 8; j++) acc[j] = 0.0;

#pragma unroll 2
  for (int e = 0; e < 64; e++) {
    double w = (double)W[(size_t)(e0 + e) * EMB + k];
#pragma unroll
    for (int j = 0; j < 8; j++)
      acc[j] += w * (double)cent[(size_t)(cbase + j) * EMB + e0 + e];
  }
  // store [es][c][k]: per-lane consecutive k -> 512B coalesced per j
#pragma unroll
  for (int j = 0; j < 8; j++)
    part[((size_t)blockIdx.x * NC + cbase + j) * EMB + k] = acc[j];
}

// prep stage 2: WcT[k][c] = sum_{es ascending} partial[es][c][k]  (globally e-ascending
// f64 order, deterministic).
__global__ void __launch_bounds__(256) prep_reduce_kernel(
    const double* __restrict__ partQ, const double* __restrict__ partK,
    double* __restrict__ WcTq, double* __restrict__ WcTk)
{
  int id = blockIdx.x * 256 + threadIdx.x;        // 0 .. 2*NC*EMB-1
  const double* part; double* WcT; int local;
  if (id < NC * EMB) { part = partQ; WcT = WcTq; local = id; }
  else               { part = partK; WcT = WcTk; local = id - NC * EMB; }
  int c = local >> 10, k = local & 1023;
  double s = 0.0;
  for (int es = 0; es < 16; es++)
    s += part[((size_t)es * NC + c) * EMB + k];
  WcT[(size_t)k * NC + c] = s;
}

// bd[c] = sum_e bias[e]*cent[c][e] — bit-identical replica of the old prep_wc bd path
// (8 g-groups of 128 consecutive e, then g-ordered sum). blockIdx.x: 0=q, 1=k.
__global__ void __launch_bounds__(256) prep_bd_kernel(
    const float* __restrict__ bq_, const float* __restrict__ cq_,
    const float* __restrict__ bk_, const float* __restrict__ ck_,
    double* __restrict__ bdq, double* __restrict__ bdk)
{
  const float* bias; const float* cent; double* bd;
  if (blockIdx.x == 0) { bias = bq_; cent = cq_; bd = bdq; }
  else                 { bias = bk_; cent = ck_; bd = bdk; }
  int tid = threadIdx.x;
  int c = tid & 31, g = tid >> 5;
  __shared__ double red[8][32];
  double s2 = 0.0;
  for (int e = g * 128; e < (g + 1) * 128; e++)
    s2 += (double)bias[e] * (double)cent[(size_t)c * EMB + e];
  red[g][c] = s2;
  __syncthreads();
  if (tid < 32) {
    double t = 0.0;
#pragma unroll
    for (int gg = 0; gg < 8; gg++) t += red[gg][tid];
    bd[tid] = t;
  }
}

// Assignment from RAW f32 input rows via WcT: f64 dots, first-max argmax.
// R3-validated version (63.8us). LDS-tiled: block = 16 rows x 32 clusters; per 64-k chunk,
// stage WcT chunk (16 KB, natural [k][c] layout) + X rows as f64 (8 KB) in LDS; inner loop
// LDS-resident. (R4's f64-MFMA rewrite FAILED: unverified f64 fragment layout — reverted.)
__global__ void __launch_bounds__(256, 2) assign2_kernel(
    const float* __restrict__ Xq, const double* __restrict__ WcTq, const double* __restrict__ bdq,
    int* __restrict__ qcl, int* __restrict__ qcnt,
    const float* __restrict__ Xk, const double* __restrict__ WcTk, const double* __restrict__ bdk,
    int* __restrict__ kcl, int* __restrict__ kcnt)
{
  const float* X; const double* WcT; const double* bd; int* cluster; int* count;
  if (blockIdx.y == 0) { X = Xq; WcT = WcTq; bd = bdq; cluster = qcl; count = qcnt; }
  else                 { X = Xk; WcT = WcTk; bd = bdk; cluster = kcl; count = kcnt; }

  int r0 = blockIdx.x * 16;
  int tid = threadIdx.x;
  int c = tid & 31, g = tid >> 5;

  __shared__ __align__(16) double Ws[64][32];   // [kk][c], 16 KB
  __shared__ __align__(16) double Xd[16][64];   // [row][kk], 8 KB

  double aAe = 0, aAo = 0, aBe = 0, aBo = 0;    // 2 rows x (even,odd) chains

  for (int k0 = 0; k0 < EMB; k0 += 64) {
    __syncthreads();                             // prev chunk compute done
    // stage WcT chunk: 2048 doubles, 8/thread, fully coalesced (512 B / wave-instr)
#pragma unroll
    for (int it = 0; it < 8; it++) {
      int idx = it * 256 + tid;
      ((double*)Ws)[idx] = WcT[(size_t)k0 * NC + idx];
    }
    // stage X chunk as f64: 1024 floats, float2/thread x2, coalesced
#pragma unroll
    for (int it = 0; it < 2; it++) {
      int idx = it * 256 + tid;
      int r = idx >> 5, kp = idx & 31;
      float2 xv = *(const float2*)(X + (size_t)(r0 + r) * EMB + k0 + kp * 2);
      double2 xd; xd.x = (double)xv.x; xd.y = (double)xv.y;
      *(double2*)(&Xd[r][kp * 2]) = xd;
    }
    __syncthreads();                             // tiles ready
#pragma unroll
    for (int kk = 0; kk < 64; kk += 2) {
      double w0 = Ws[kk][c], w1 = Ws[kk + 1][c];
      double2 xa = *(const double2*)(&Xd[g * 2][kk]);
      double2 xb = *(const double2*)(&Xd[g * 2 + 1][kk]);
      aAe += xa.x * w0; aAo += xa.y * w1;
      aBe += xb.x * w0; aBo += xb.y * w1;
    }
  }

  double dA = (aAe + aAo) + bd[c];
  double dB = (aBe + aBo) + bd[c];

  // argmax over c within each 32-lane half, both rows (first-max: lowest index wins ties)
  double bvA = dA; int biA = c;
  double bvB = dB; int biB = c;
#pragma unroll
  for (int off = 1; off < 32; off <<= 1) {
    double ovA = __shfl_xor(bvA, off, 64); int oiA = __shfl_xor(biA, off, 64);
    if (ovA > bvA || (ovA == bvA && oiA < biA)) { bvA = ovA; biA = oiA; }
    double ovB = __shfl_xor(bvB, off, 64); int oiB = __shfl_xor(biB, off, 64);
    if (ovB > bvB || (ovB == bvB && oiB < biB)) { bvB = ovB; biB = oiB; }
  }
  if (c == 0) {
    int rowA = r0 + g * 2, rowB = rowA + 1;
    cluster[rowA] = biA; atomicAdd(&count[(rowA & 1) * NC + biA], 1);
    cluster[rowB] = biB; atomicAdd(&count[(rowB & 1) * NC + biB], 1);
  }
}

__global__ void scan_kernel(const int* __restrict__ qcount, const int* __restrict__ kcount,
                            int* __restrict__ qoff, int* __restrict__ koff)
{
  int tid = threadIdx.x;
  if (tid < 2) {
    int run = 0;
    for (int c = 0; c < NC; c++) { qoff[tid * NC + c] = run; run += qcount[tid * NC + c]; }
  } else if (tid < 4) {
    int n = tid - 2, run = 0;
    for (int c = 0; c < NC; c++) { koff[n * NC + c] = run; run += kcount[n * NC + c]; }
  }
}

__global__ void __launch_bounds__(256) scatter_kernel(
    const int* __restrict__ q_cluster, const int* __restrict__ k_cluster,
    const int* __restrict__ qoff, const int* __restrict__ koff,
    int* __restrict__ qfill, int* __restrict__ kfill,
    int* __restrict__ qlist, int* __restrict__ klist)
{
  int id = blockIdx.x * 256 + threadIdx.x;
  if (id < MROWS) {
    int row = id, n = row & 1, l = row >> 1, c = q_cluster[row];
    int pos = atomicAdd(&qfill[n * NC + c], 1);
    qlist[n * L_SEQ + qoff[n * NC + c] + pos] = l;
  } else {
    int row = id - MROWS, n = row & 1, s = row >> 1, c = k_cluster[row];
    int pos = atomicAdd(&kfill[n * NC + c], 1);
    klist[n * S_SEQ + koff[n * NC + c] + pos] = s;
  }
}

// Bucketed attention, MFMA flash-style. Block=(cluster,head,batch), 4 waves, 16 queries/wave,
// 64-key chunks with online softmax. Swapped operands keep softmax per-lane-uniform:
//   S^T = mfma(A=K, B=Q)    -> D[row=key=4g+r][col=q=lane&15]
//   O^T = mfma(A=V^T, B=P^T)-> D[row=d  =4g+r][col=q=lane&15]
// so running max / lsum / rescale are one scalar per lane (reduce = shfl_xor 16,32).
// P^T relayout through wave-private LDS; all LDS tiles row-XOR-swizzled. (R1-validated.)
__global__ void __launch_bounds__(256) attn_bucket(
    const unsigned short* __restrict__ Qb, const unsigned short* __restrict__ Kb,
    const unsigned short* __restrict__ Vb,
    const int* __restrict__ qcount, const int* __restrict__ qoff, const int* __restrict__ qlist,
    const int* __restrict__ kcount, const int* __restrict__ koff, const int* __restrict__ klist,
    unsigned short* __restrict__ ctx)
{
  int c = blockIdx.x, h = blockIdx.y, n = blockIdx.z;
  int Sc = kcount[n * NC + c], k0base = koff[n * NC + c];
  int Lc = qcount[n * NC + c], q0 = qoff[n * NC + c];
  int tid = threadIdx.x, wave = tid >> 6, lane = tid & 63;
  int lg = lane >> 4, lq = lane & 15;

  __shared__ __align__(16) unsigned short Ks[64][64];    // [key][d], row-swizzled
  __shared__ __align__(16) unsigned short Vts[64][64];   // [d][key], row-swizzled
  __shared__ __align__(16) unsigned short Pts[4][16][64]; // per-wave [q][key], row-swizzled
  __shared__ int rb[64];                                  // gathered K/V row base offsets

  if (Sc == 0) {   // no keys: ref softmax would be NaN; R9 proved this never occurs. Write 0.
    for (int qi = wave; qi < Lc; qi += 4) {
      int l = qlist[n * L_SEQ + q0 + qi];
      ctx[((size_t)(n * L_SEQ + l)) * EMB + h * DH + lane] = 0;
    }
    return;
  }

  const int* kl = klist + n * S_SEQ + k0base;
  const int* ql = qlist + n * L_SEQ + q0;
  f32x4 zero = {0.f, 0.f, 0.f, 0.f};

  for (int qb = 0; qb < Lc; qb += 64) {           // uniform trip count across waves
    int qq = qb + wave * 16 + lq;
    int qqc = qq < Lc ? qq : Lc - 1;              // clamp: padded lanes duplicate last query
    int lrow = ql[qqc];
    const unsigned short* qp = Qb + ((size_t)(lrow * NB + n)) * EMB + h * DH;
    bf16x8 qf0 = *(const bf16x8*)(qp + lg * 8);          // B=Q frag: col=q, k=d 0..31
    bf16x8 qf1 = *(const bf16x8*)(qp + 32 + lg * 8);     //                  d 32..63

    f32x4 acc[4];                                  // O^T: 4 d-tiles, col=q per lane
#pragma unroll
    for (int di = 0; di < 4; di++) acc[di] = zero;
    float m = -3.0e38f, lsum = 0.f;

    for (int kc = 0; kc < Sc; kc += 64) {
      __syncthreads();                             // prev chunk compute done
      if (tid < 64) {
        int jj = kc + tid; if (jj >= Sc) jj = Sc - 1;   // clamp-pad: valid finite rows
        rb[tid] = (kl[jj] * NB + n) * EMB + h * DH;
      }
      __syncthreads();                             // rb ready
#pragma unroll
      for (int it = 0; it < 2; it++) {
        int p = it * 256 + tid;                    // 512 pieces
        {                                          // K: [key][d] 16B pieces
          int row = p >> 3, seg = p & 7;
          uint4 u = *(const uint4*)(Kb + rb[row] + seg * 8);
          *(uint4*)(&Ks[row][(seg * 8) ^ ((row & 7) << 3)]) = u;
        }
        {                                          // V^T: gather column d, 8 keys
          int d = p & 63, kg = p >> 6;
          unsigned short v0 = Vb[rb[kg * 8 + 0] + d], v1 = Vb[rb[kg * 8 + 1] + d];
          unsigned short v2 = Vb[rb[kg * 8 + 2] + d], v3 = Vb[rb[kg * 8 + 3] + d];
          unsigned short v4 = Vb[rb[kg * 8 + 4] + d], v5 = Vb[rb[kg * 8 + 5] + d];
          unsigned short v6 = Vb[rb[kg * 8 + 6] + d], v7 = Vb[rb[kg * 8 + 7] + d];
          uint4 u;
          u.x = (uint32_t)v0 | ((uint32_t)v1 << 16);
          u.y = (uint32_t)v2 | ((uint32_t)v3 << 16);
          u.z = (uint32_t)v4 | ((uint32_t)v5 << 16);
          u.w = (uint32_t)v6 | ((uint32_t)v7 << 16);
          *(uint4*)(&Vts[d][(kg * 8) ^ ((d & 7) << 3)]) = u;
        }
      }
      __syncthreads();                             // K/V^T staged

      // S^T = K @ Q^T : 4 key-tiles x 2 d-steps
      f32x4 st[4];
#pragma unroll
      for (int ni = 0; ni < 4; ni++) st[ni] = zero;
#pragma unroll
      for (int ni = 0; ni < 4; ni++) {
        int row = ni * 16 + lq;
        bf16x8 kf0 = *(const bf16x8*)(&Ks[row][(lg * 8) ^ ((row & 7) << 3)]);
        bf16x8 kf1 = *(const bf16x8*)(&Ks[row][(32 + lg * 8) ^ ((row & 7) << 3)]);
        st[ni] = __builtin_amdgcn_mfma_f32_16x16x32_bf16(kf0, qf0, st[ni], 0, 0, 0);
        st[ni] = __builtin_amdgcn_mfma_f32_16x16x32_bf16(kf1, qf1, st[ni], 0, 0, 0);
      }

      // online softmax (per-lane scalar state; clamp-padded keys duplicate valid
      // scores so they cannot change the max; they are zeroed in p below)
      int lim = Sc - kc;
      float cm = -3.0e38f;
#pragma unroll
      for (int ni = 0; ni < 4; ni++) {
        st[ni] = st[ni] * 0.125f;                  // 1/sqrt(64)
#pragma unroll
        for (int r = 0; r < 4; r++) cm = fmaxf(cm, st[ni][r]);
      }
      cm = fmaxf(cm, __shfl_xor(cm, 16, 64));
      cm = fmaxf(cm, __shfl_xor(cm, 32, 64));
      float mn = fmaxf(m, cm);
      float fac = __expf(m - mn);
      m = mn;
      lsum *= fac;
#pragma unroll
      for (int di = 0; di < 4; di++) acc[di] = acc[di] * fac;

      // P^T -> LDS (bf16); lsum over ROUNDED p so O stays a true weighted average
#pragma unroll
      for (int ni = 0; ni < 4; ni++) {
        int kloc = ni * 16 + lg * 4;
        float p0 = (kloc + 0 < lim) ? __expf(st[ni][0] - mn) : 0.f;
        float p1 = (kloc + 1 < lim) ? __expf(st[ni][1] - mn) : 0.f;
        float p2 = (kloc + 2 < lim) ? __expf(st[ni][2] - mn) : 0.f;
        float p3 = (kloc + 3 < lim) ? __expf(st[ni][3] - mn) : 0.f;
        unsigned short b0 = f2bf(p0), b1 = f2bf(p1), b2 = f2bf(p2), b3 = f2bf(p3);
        lsum += bf2f(b0) + bf2f(b1) + bf2f(b2) + bf2f(b3);
        ushort4 u4; u4.x = b0; u4.y = b1; u4.z = b2; u4.w = b3;
        *(ushort4*)(&Pts[wave][lq][kloc ^ ((lq & 7) << 3)]) = u4;
      }

      // O^T += V^T @ P^T : 4 d-tiles x 2 key-steps
#pragma unroll
      for (int ks = 0; ks < 2; ks++) {
        bf16x8 pf = *(const bf16x8*)(&Pts[wave][lq][(ks * 32 + lg * 8) ^ ((lq & 7) << 3)]);
#pragma unroll
        for (int di = 0; di < 4; di++) {
          int row = di * 16 + lq;
          bf16x8 vf = *(const bf16x8*)(&Vts[row][(ks * 32 + lg * 8) ^ ((row & 7) << 3)]);
          acc[di] = __builtin_amdgcn_mfma_f32_16x16x32_bf16(vf, pf, acc[di], 0, 0, 0);
        }
      }
    }

    lsum += __shfl_xor(lsum, 16, 64);
    lsum += __shfl_xor(lsum, 32, 64);
    float rinv = 1.f / lsum;
    if (qq < Lc) {                                 // padded duplicates skip the store
      unsigned short* op = ctx + ((size_t)(n * L_SEQ + lrow)) * EMB + h * DH;
#pragma unroll
      for (int di = 0; di < 4; di++) {
        ushort4 o;
        o.x = f2bf(acc[di][0] * rinv);
        o.y = f2bf(acc[di][1] * rinv);
        o.z = f2bf(acc[di][2] * rinv);
        o.w = f2bf(acc[di][3] * rinv);
        *(ushort4*)(op + di * 16 + lg * 4) = o;    // d = di*16 + 4g + r, contiguous r
      }
    }
  }
}

// Residual + LayerNorm, f32 output. out row r = l*NB+n; proj row = n*L+l. (R9-validated.)
__global__ void __launch_bounds__(256) ln_kernel(
    const float* __restrict__ proj, const float* __restrict__ query,
    const float* __restrict__ gamma, const float* __restrict__ beta,
    float* __restrict__ out)
{
  int r = blockIdx.x;
  int l = r >> 1, n = r & 1;
  int tid = threadIdx.x, wave = tid >> 6, lane = tid & 63;
  float4 p = *(const float4*)(proj + ((size_t)(n * L_SEQ + l)) * EMB + tid * 4);
  float4 qu = *(const float4*)(query + (size_t)r * EMB + tid * 4);
  float res[4] = { p.x + qu.x, p.y + qu.y, p.z + qu.z, p.w + qu.w };
  float s1 = res[0] + res[1] + res[2] + res[3];
  float s2 = res[0] * res[0] + res[1] * res[1] + res[2] * res[2] + res[3] * res[3];
#pragma unroll
  for (int off = 32; off; off >>= 1) {
    s1 += __shfl_xor(s1, off, 64);
    s2 += __shfl_xor(s2, off, 64);
  }
  __shared__ float a1[4], a2[4];
  if (lane == 0) { a1[wave] = s1; a2[wave] = s2; }
  __syncthreads();
  float t1 = a1[0] + a1[1] + a1[2] + a1[3];
  float t2 = a2[0] + a2[1] + a2[2] + a2[3];
  float mu = t1 * (1.f / EMB);
  float var = fmaxf(t2 * (1.f / EMB) - mu * mu, 0.f);
  float rstd = 1.f / sqrtf(var + 1e-5f);
  float4 gu = *(const float4*)(gamma + tid * 4);
  float4 bu = *(const float4*)(beta + tid * 4);
  float4 o;
  o.x = (res[0] - mu) * rstd * gu.x + bu.x;
  o.y = (res[1] - mu) * rstd * gu.y + bu.y;
  o.z = (res[2] - mu) * rstd * gu.z + bu.z;
  o.w = (res[3] - mu) * rstd * gu.w + bu.w;
  *(float4*)(out + (size_t)r * EMB + tid * 4) = o;
}

extern "C" void kernel_launch(void* const* d_in, const int* in_sizes, int n_in,
                              void* d_out, int out_size, void* d_ws, size_t ws_size,
                              hipStream_t stream) {
  const float* query = (const float*)d_in[0];
  const float* key   = (const float*)d_in[1];
  const float* value = (const float*)d_in[2];
  const float* Wq = (const float*)d_in[3];
  const float* bq = (const float*)d_in[4];
  const float* Wk = (const float*)d_in[5];
  const float* bk = (const float*)d_in[6];
  const float* Wv = (const float*)d_in[7];
  const float* bv = (const float*)d_in[8];
  const float* Wo = (const float*)d_in[9];
  const float* bo = (const float*)d_in[10];
  const float* cq = (const float*)d_in[11];
  const float* ck = (const float*)d_in[12];
  const float* gamma = (const float*)d_in[13];
  const float* beta  = (const float*)d_in[14];
  float* out = (float*)d_out;   // f32 output (reference dtype)

  const size_t MB_EL = (size_t)MROWS * EMB;   // 4M elements

  // workspace (~35 MB): control block first, then bf16 tensors; proj aliases Qb+Kb;
  // xbf (bf16 input scratch) aliases ctx (dead until attention); wbf appended (2 MB);
  // prep partials (8 MB) alias Qb (dead until first GEMM, which runs after prep_reduce).
  int* q_cluster = (int*)d_ws;               // 16 KB
  int* k_cluster = q_cluster + MROWS;        // 16 KB
  int* qcount = k_cluster + MROWS;           // 6 x 64 ints contiguous (one memset)
  int* kcount = qcount + 64;
  int* qoff   = kcount + 64;
  int* koff   = qoff + 64;
  int* qfill  = koff + 64;
  int* kfill  = qfill + 64;
  int* qlist  = kfill + 64;                  // [2][2048]
  int* klist  = qlist + MROWS;               // [2][2048]
  double* Wcq = (double*)(klist + MROWS);    // 256 KB (offset 67072, 16B-aligned) [k][c] layout
  double* Wck = Wcq + (size_t)NC * EMB;      // 256 KB [k][c] layout
  double* bdq = Wck + (size_t)NC * EMB;
  double* bdk = bdq + NC;
  unsigned short* Qb  = (unsigned short*)(bdk + NC);  // 8 MB bf16, row = seq*2+n
  unsigned short* Kb  = Qb + MB_EL;                   // 8 MB
  unsigned short* Vb  = Kb + MB_EL;                   // 8 MB
  unsigned short* ctx = Vb + MB_EL;                   // 8 MB, row = n*L+l
  unsigned short* wbf = ctx + MB_EL;                  // 2 MB bf16 weight scratch (reused 4x)
  unsigned short* xbf = ctx;   // bf16 input scratch overlays ctx (dead until attn writes it)
  float* proj = (float*)Qb;    // 16 MB f32 overlays Qb+Kb (dead after attention)
  double* partQ = (double*)Qb; // 4 MB prep partials overlay Qb (consumed before GEMM 1)
  double* partK = partQ + (size_t)16 * NC * EMB;      // 4 MB

  const int W8 = (EMB * EMB) / 8;     // 131072 -> 512 blocks
  const int X8 = (int)(MB_EL / 8);    // 524288 -> 2048 blocks

  hipMemsetAsync(qcount, 0, 6 * 64 * sizeof(int), stream);

  prep_partial_kernel<<<dim3(16, 16, 2), 256, 0, stream>>>(Wq, cq, Wk, ck, partQ, partK);
  prep_reduce_kernel<<<(2 * NC * EMB) / 256, 256, 0, stream>>>(partQ, partK, Wcq, Wck);
  prep_bd_kernel<<<2, 256, 0, stream>>>(bq, cq, bk, ck, bdq, bdk);

  dim3 gg(EMB / 128, MROWS / 128);
  conv_f2bf_kernel<<<W8 / 256, 256, 0, stream>>>(Wq, wbf, W8);
  conv_f2bf_kernel<<<X8 / 256, 256, 0, stream>>>(query, xbf, X8);
  gemm_bt_mfma<<<gg, 256, 0, stream>>>(xbf, wbf, bq, nullptr, Qb);

  conv_f2bf_kernel<<<W8 / 256, 256, 0, stream>>>(Wk, wbf, W8);
  conv_f2bf_kernel<<<X8 / 256, 256, 0, stream>>>(key, xbf, X8);
  gemm_bt_mfma<<<gg, 256, 0, stream>>>(xbf, wbf, bk, nullptr, Kb);

  conv_f2bf_kernel<<<W8 / 256, 256, 0, stream>>>(Wv, wbf, W8);
  conv_f2bf_kernel<<<X8 / 256, 256, 0, stream>>>(value, xbf, X8);
  gemm_bt_mfma<<<gg, 256, 0, stream>>>(xbf, wbf, bv, nullptr, Vb);

  assign2_kernel<<<dim3(MROWS / 16, 2), 256, 0, stream>>>(
      query, Wcq, bdq, q_cluster, qcount,
      key,   Wck, bdk, k_cluster, kcount);

  scan_kernel<<<1, 64, 0, stream>>>(qcount, kcount, qoff, koff);
  scatter_kernel<<<(2 * MROWS) / 256, 256, 0, stream>>>(q_cluster, k_cluster, qoff, koff,
                                                        qfill, kfill, qlist, klist);
  attn_bucket<<<dim3(NC, NH, NB), 256, 0, stream>>>(Qb, Kb, Vb, qcount, qoff, qlist,
                                                    kcount, koff, klist, ctx);

  conv_f2bf_kernel<<<W8 / 256, 256, 0, stream>>>(Wo, wbf, W8);
  gemm_bt_mfma<<<gg, 256, 0, stream>>>(ctx, wbf, bo, proj, nullptr);
  ln_kernel<<<MROWS, 256, 0, stream>>>(proj, query, gamma, beta, out);
}

// Round 8
// 357.632 us; speedup vs baseline: 1.5311x; 1.0342x over previous
//
#include <hip/hip_runtime.h>
#include <stdint.h>

#define L_SEQ 2048
#define S_SEQ 2048
#define NB 2
#define EMB 1024
#define NH 16
#define DH 64
#define NC 32
#define MROWS 4096  // L*N

typedef __bf16 bf16x8 __attribute__((ext_vector_type(8)));
typedef float f32x4 __attribute__((ext_vector_type(4)));

__device__ __forceinline__ float bf2f(unsigned short u) {
  return __builtin_bit_cast(float, (uint32_t)u << 16);
}
__device__ __forceinline__ unsigned short f2bf(float f) {
  uint32_t u = __builtin_bit_cast(uint32_t, f);
  return (unsigned short)((u + 0x7FFFu + ((u >> 16) & 1u)) >> 16);
}

// Async global->LDS staging (m97 lever). LDS dest is wave-uniform base + lane*16 in our
// staging pattern (consecutive tid -> consecutive 16B LDS chunks), which is the documented
// contract. Fallback: plain vector copy (same data, VGPR round-trip).
#if defined(__has_builtin) && __has_builtin(__builtin_amdgcn_global_load_lds)
#define GLOAD_LDS(gp, lp)                                            \
  __builtin_amdgcn_global_load_lds(                                  \
      (const __attribute__((address_space(1))) void*)(gp),           \
      (__attribute__((address_space(3))) void*)(lp), 16, 0, 0)
#else
#define GLOAD_LDS(gp, lp) do { *(uint4*)(lp) = *(const uint4*)(gp); } while (0)
#endif

// f32 -> bf16 RNE convert for W (region 1) + X (region 2) in ONE launch (launch-count diet).
// Same f2bf as validated inline path -> bit-identical GEMM inputs. srcX may be null.
__global__ void __launch_bounds__(256) conv_f2bf_kernel(
    const float* __restrict__ srcW, unsigned short* __restrict__ dstW, int nW8,
    const float* __restrict__ srcX, unsigned short* __restrict__ dstX, int nX8)
{
  int id = blockIdx.x * 256 + threadIdx.x;
  const float* src; unsigned short* dst; int i;
  if (id < nW8) { src = srcW; dst = dstW; i = id; }
  else { i = id - nW8; if (i >= nX8) return; src = srcX; dst = dstX; }
  const float4* s = (const float4*)src + (size_t)i * 2;
  float4 a0 = s[0], a1 = s[1];
  uint4 u;
  u.x = (uint32_t)f2bf(a0.x) | ((uint32_t)f2bf(a0.y) << 16);
  u.y = (uint32_t)f2bf(a0.z) | ((uint32_t)f2bf(a0.w) << 16);
  u.z = (uint32_t)f2bf(a1.x) | ((uint32_t)f2bf(a1.y) << 16);
  u.w = (uint32_t)f2bf(a1.z) | ((uint32_t)f2bf(a1.w) << 16);
  ((uint4*)dst)[i] = u;
}

// C = A @ B^T + bias. MFMA bf16, 128x128 tile (m93/m97-validated frag/epilogue structure).
// Both operands bf16 (pre-converted) -> staging is pure global_load_lds width-16
// (4 calls/thread/K-step), no VALU conversion in the loop. Out: f32 if outF, else bf16.
__global__ void __launch_bounds__(256) gemm_bt_mfma(
    const unsigned short* __restrict__ A, const unsigned short* __restrict__ B,
    const float* __restrict__ bias,
    float* __restrict__ outF, unsigned short* __restrict__ outB)
{
  __shared__ __align__(16) unsigned short As[128][32];  // unpadded 64B rows (b128-aligned)
  __shared__ __align__(16) unsigned short Bs[128][32];
  const int K = EMB;
  int tid = threadIdx.x;
  int m0 = blockIdx.y * 128, n0 = blockIdx.x * 128;
  int wave = tid >> 6, lane = tid & 63;
  int wm = (wave >> 1) * 64, wn = (wave & 1) * 64;

  f32x4 zero = {0.f, 0.f, 0.f, 0.f};
  f32x4 acc[4][4];
#pragma unroll
  for (int mi = 0; mi < 4; mi++)
#pragma unroll
    for (int ni = 0; ni < 4; ni++) acc[mi][ni] = zero;

  int fr = lane & 15, fk = (lane >> 4) * 8;

  for (int k0 = 0; k0 < K; k0 += 32) {
    __syncthreads();
#pragma unroll
    for (int it = 0; it < 2; it++) {
      int ch = tid + it * 256;          // 512 chunks of 8 bf16 per tile
      int row = ch >> 2, kk = (ch & 3) * 8;
      GLOAD_LDS(A + (size_t)(m0 + row) * K + k0 + kk, &As[row][kk]);
      GLOAD_LDS(B + (size_t)(n0 + row) * K + k0 + kk, &Bs[row][kk]);
    }
    __syncthreads();
    bf16x8 af[4], bfr[4];
#pragma unroll
    for (int i = 0; i < 4; i++) af[i] = *(const bf16x8*)(&As[wm + i * 16 + fr][fk]);
#pragma unroll
    for (int i = 0; i < 4; i++) bfr[i] = *(const bf16x8*)(&Bs[wn + i * 16 + fr][fk]);
#pragma unroll
    for (int mi = 0; mi < 4; mi++)
#pragma unroll
      for (int ni = 0; ni < 4; ni++)
        acc[mi][ni] = __builtin_amdgcn_mfma_f32_16x16x32_bf16(af[mi], bfr[ni], acc[mi][ni], 0, 0, 0);
  }

#pragma unroll
  for (int ni = 0; ni < 4; ni++) {
    int col = n0 + wn + ni * 16 + (lane & 15);
    float bv = bias[col];
#pragma unroll
    for (int mi = 0; mi < 4; mi++) {
#pragma unroll
      for (int r = 0; r < 4; r++) {
        int row = m0 + wm + mi * 16 + (lane >> 4) * 4 + r;
        float v = acc[mi][ni][r] + bv;
        if (outF) outF[(size_t)row * EMB + col] = v;
        else outB[(size_t)row * EMB + col] = f2bf(v);
      }
    }
  }
}

// prep stage 1: partial[es][c][k] = sum_{e in es-chunk, ascending} W[e][k]*cent[c][e], f64.
// (R7-validated: prep family now ~7us.) W reads coalesced 256B row-runs; cent rows
// wave-uniform (readfirstlane -> s_load); 8 independent f64 FMA chains.
__global__ void __launch_bounds__(256) prep_partial_kernel(
    const float* __restrict__ Wq_, const float* __restrict__ cq_,
    const float* __restrict__ Wk_, const float* __restrict__ ck_,
    double* __restrict__ partQ, double* __restrict__ partK)
{
  const float* W; const float* cent; double* part;
  if (blockIdx.z == 0) { W = Wq_; cent = cq_; part = partQ; }
  else                 { W = Wk_; cent = ck_; part = partK; }
  int tid = threadIdx.x;
  int k = (blockIdx.y << 6) | (tid & 63);
  int cbase = __builtin_amdgcn_readfirstlane(tid >> 6) * 8;   // wave-uniform -> s_load path
  int e0 = blockIdx.x << 6;

  double acc[8];
#pragma unroll
  for (int j = 0; j < 8; j++) acc[j] = 0.0;

#pragma unroll 2
  for (int e = 0; e < 64; e++) {
    double w = (double)W[(size_t)(e0 + e) * EMB + k];
#pragma unroll
    for (int j = 0; j < 8; j++)
      acc[j] += w * (double)cent[(size_t)(cbase + j) * EMB + e0 + e];
  }
#pragma unroll
  for (int j = 0; j < 8; j++)
    part[((size_t)blockIdx.x * NC + cbase + j) * EMB + k] = acc[j];
}

// prep stage 2: WcT[k][c] = sum_{es ascending} partial[es][c][k]  (globally e-ascending
// f64 order, deterministic).
__global__ void __launch_bounds__(256) prep_reduce_kernel(
    const double* __restrict__ partQ, const double* __restrict__ partK,
    double* __restrict__ WcTq, double* __restrict__ WcTk)
{
  int id = blockIdx.x * 256 + threadIdx.x;        // 0 .. 2*NC*EMB-1
  const double* part; double* WcT; int local;
  if (id < NC * EMB) { part = partQ; WcT = WcTq; local = id; }
  else               { part = partK; WcT = WcTk; local = id - NC * EMB; }
  int c = local >> 10, k = local & 1023;
  double s = 0.0;
  for (int es = 0; es < 16; es++)
    s += part[((size_t)es * NC + c) * EMB + k];
  WcT[(size_t)k * NC + c] = s;
}

// bd[c] = sum_e bias[e]*cent[c][e] — bit-identical replica of the original bd path
// (8 g-groups of 128 consecutive e, then g-ordered sum). blockIdx.x: 0=q, 1=k.
__global__ void __launch_bounds__(256) prep_bd_kernel(
    const float* __restrict__ bq_, const float* __restrict__ cq_,
    const float* __restrict__ bk_, const float* __restrict__ ck_,
    double* __restrict__ bdq, double* __restrict__ bdk)
{
  const float* bias; const float* cent; double* bd;
  if (blockIdx.x == 0) { bias = bq_; cent = cq_; bd = bdq; }
  else                 { bias = bk_; cent = ck_; bd = bdk; }
  int tid = threadIdx.x;
  int c = tid & 31, g = tid >> 5;
  __shared__ double red[8][32];
  double s2 = 0.0;
  for (int e = g * 128; e < (g + 1) * 128; e++)
    s2 += (double)bias[e] * (double)cent[(size_t)c * EMB + e];
  red[g][c] = s2;
  __syncthreads();
  if (tid < 32) {
    double t = 0.0;
#pragma unroll
    for (int gg = 0; gg < 8; gg++) t += red[gg][tid];
    bd[tid] = t;
  }
}

// Assignment from RAW f32 input rows via WcT: f64 dots, first-max argmax.
// R7 post-mortem: old version LDS-ISSUE bound on X broadcast b128 reads (16B useful per
// 12-cyc instr; model 61us == 63us measured). This version cuts broadcast instrs 4x:
// (1) X staged f32 (one b128 = 4 k; inputs are f32 so cvt-at-use is exact — the f64
// PRODUCT/SUM contract is unchanged), (2) 4 rows per c-group with Ws register-cached
// per 8-k step. Chip LDS model: 256 blk x 4 waves x 128 steps x 144 cyc -> ~31us.
// Summation-order change = pure f64 reassociation (same acceptance class as R2->R3).
// Argmax/tie semantics identical (first-max shfl reduce). blockIdx.y: 0=query, 1=key.
__global__ void __launch_bounds__(256) assign2_kernel(
    const float* __restrict__ Xq, const double* __restrict__ WcTq, const double* __restrict__ bdq,
    int* __restrict__ qcl, int* __restrict__ qcnt,
    const float* __restrict__ Xk, const double* __restrict__ WcTk, const double* __restrict__ bdk,
    int* __restrict__ kcl, int* __restrict__ kcnt)
{
  const float* X; const double* WcT; const double* bd; int* cluster; int* count;
  if (blockIdx.y == 0) { X = Xq; WcT = WcTq; bd = bdq; cluster = qcl; count = qcnt; }
  else                 { X = Xk; WcT = WcTk; bd = bdk; cluster = kcl; count = kcnt; }

  int r0 = blockIdx.x * 32;                       // 32 rows/block
  int tid = threadIdx.x;
  int c = tid & 31, g = tid >> 5;                 // 8 groups x 4 rows
  int g4 = g * 4;

  __shared__ __align__(16) double Ws[64][32];     // [kk][c] f64, 16 KB
  __shared__ __align__(16) float  Xs[32][64];     // [row][kk] f32, 8 KB

  double a[4][4];                                 // 4 rows x 4 k-phase chains
#pragma unroll
  for (int rr = 0; rr < 4; rr++)
#pragma unroll
    for (int j = 0; j < 4; j++) a[rr][j] = 0.0;

  for (int k0 = 0; k0 < EMB; k0 += 64) {
    __syncthreads();                              // prev chunk compute done
    // stage WcT chunk: 2048 doubles, 8/thread, coalesced
#pragma unroll
    for (int it = 0; it < 8; it++) {
      int idx = it * 256 + tid;
      ((double*)Ws)[idx] = WcT[(size_t)k0 * NC + idx];
    }
    // stage X chunk f32: 512 float4 pieces, 2/thread, coalesced
#pragma unroll
    for (int it = 0; it < 2; it++) {
      int idx = it * 256 + tid;
      int r = idx >> 4, kp = (idx & 15) * 4;
      *(float4*)(&Xs[r][kp]) = *(const float4*)(X + (size_t)(r0 + r) * EMB + k0 + kp);
    }
    __syncthreads();                              // tiles ready
#pragma unroll
    for (int ks = 0; ks < 64; ks += 8) {
      double w0 = Ws[ks + 0][c], w1 = Ws[ks + 1][c];
      double w2 = Ws[ks + 2][c], w3 = Ws[ks + 3][c];
      double w4 = Ws[ks + 4][c], w5 = Ws[ks + 5][c];
      double w6 = Ws[ks + 6][c], w7 = Ws[ks + 7][c];
#pragma unroll
      for (int rr = 0; rr < 4; rr++) {
        float4 xa = *(const float4*)(&Xs[g4 + rr][ks]);
        float4 xb = *(const float4*)(&Xs[g4 + rr][ks + 4]);
        a[rr][0] += (double)xa.x * w0; a[rr][1] += (double)xa.y * w1;
        a[rr][2] += (double)xa.z * w2; a[rr][3] += (double)xa.w * w3;
        a[rr][0] += (double)xb.x * w4; a[rr][1] += (double)xb.y * w5;
        a[rr][2] += (double)xb.z * w6; a[rr][3] += (double)xb.w * w7;
      }
    }
  }

  double bdc = bd[c];
#pragma unroll
  for (int rr = 0; rr < 4; rr++) {
    double dot = ((a[rr][0] + a[rr][1]) + (a[rr][2] + a[rr][3])) + bdc;
    // argmax over c within each 32-lane half (first-max: lowest index wins ties)
    double bv = dot; int bi = c;
#pragma unroll
    for (int off = 1; off < 32; off <<= 1) {
      double ov = __shfl_xor(bv, off, 64);
      int oi = __shfl_xor(bi, off, 64);
      if (ov > bv || (ov == bv && oi < bi)) { bv = ov; bi = oi; }
    }
    if (c == 0) {
      int row = r0 + g4 + rr;
      cluster[row] = bi;
      atomicAdd(&count[(row & 1) * NC + bi], 1);
    }
  }
}

__global__ void scan_kernel(const int* __restrict__ qcount, const int* __restrict__ kcount,
                            int* __restrict__ qoff, int* __restrict__ koff)
{
  int tid = threadIdx.x;
  if (tid < 2) {
    int run = 0;
    for (int c = 0; c < NC; c++) { qoff[tid * NC + c] = run; run += qcount[tid * NC + c]; }
  } else if (tid < 4) {
    int n = tid - 2, run = 0;
    for (int c = 0; c < NC; c++) { koff[n * NC + c] = run; run += kcount[n * NC + c]; }
  }
}

__global__ void __launch_bounds__(256) scatter_kernel(
    const int* __restrict__ q_cluster, const int* __restrict__ k_cluster,
    const int* __restrict__ qoff, const int* __restrict__ koff,
    int* __restrict__ qfill, int* __restrict__ kfill,
    int* __restrict__ qlist, int* __restrict__ klist)
{
  int id = blockIdx.x * 256 + threadIdx.x;
  if (id < MROWS) {
    int row = id, n = row & 1, l = row >> 1, c = q_cluster[row];
    int pos = atomicAdd(&qfill[n * NC + c], 1);
    qlist[n * L_SEQ + qoff[n * NC + c] + pos] = l;
  } else {
    int row = id - MROWS, n = row & 1, s = row >> 1, c = k_cluster[row];
    int pos = atomicAdd(&kfill[n * NC + c], 1);
    klist[n * S_SEQ + koff[n * NC + c] + pos] = s;
  }
}

// Bucketed attention, MFMA flash-style. Block=(cluster,head,batch), 4 waves, 16 queries/wave,
// 64-key chunks with online softmax. Swapped operands keep softmax per-lane-uniform:
//   S^T = mfma(A=K, B=Q)    -> D[row=key=4g+r][col=q=lane&15]
//   O^T = mfma(A=V^T, B=P^T)-> D[row=d  =4g+r][col=q=lane&15]
// so running max / lsum / rescale are one scalar per lane (reduce = shfl_xor 16,32).
// P^T relayout through wave-private LDS; all LDS tiles row-XOR-swizzled. (R1-validated.)
__global__ void __launch_bounds__(256) attn_bucket(
    const unsigned short* __restrict__ Qb, const unsigned short* __restrict__ Kb,
    const unsigned short* __restrict__ Vb,
    const int* __restrict__ qcount, const int* __restrict__ qoff, const int* __restrict__ qlist,
    const int* __restrict__ kcount, const int* __restrict__ koff, const int* __restrict__ klist,
    unsigned short* __restrict__ ctx)
{
  int c = blockIdx.x, h = blockIdx.y, n = blockIdx.z;
  int Sc = kcount[n * NC + c], k0base = koff[n * NC + c];
  int Lc = qcount[n * NC + c], q0 = qoff[n * NC + c];
  int tid = threadIdx.x, wave = tid >> 6, lane = tid & 63;
  int lg = lane >> 4, lq = lane & 15;

  __shared__ __align__(16) unsigned short Ks[64][64];    // [key][d], row-swizzled
  __shared__ __align__(16) unsigned short Vts[64][64];   // [d][key], row-swizzled
  __shared__ __align__(16) unsigned short Pts[4][16][64]; // per-wave [q][key], row-swizzled
  __shared__ int rb[64];                                  // gathered K/V row base offsets

  if (Sc == 0) {   // no keys: ref softmax would be NaN; R9 proved this never occurs. Write 0.
    for (int qi = wave; qi < Lc; qi += 4) {
      int l = qlist[n * L_SEQ + q0 + qi];
      ctx[((size_t)(n * L_SEQ + l)) * EMB + h * DH + lane] = 0;
    }
    return;
  }

  const int* kl = klist + n * S_SEQ + k0base;
  const int* ql = qlist + n * L_SEQ + q0;
  f32x4 zero = {0.f, 0.f, 0.f, 0.f};

  for (int qb = 0; qb < Lc; qb += 64) {           // uniform trip count across waves
    int qq = qb + wave * 16 + lq;
    int qqc = qq < Lc ? qq : Lc - 1;              // clamp: padded lanes duplicate last query
    int lrow = ql[qqc];
    const unsigned short* qp = Qb + ((size_t)(lrow * NB + n)) * EMB + h * DH;
    bf16x8 qf0 = *(const bf16x8*)(qp + lg * 8);          // B=Q frag: col=q, k=d 0..31
    bf16x8 qf1 = *(const bf16x8*)(qp + 32 + lg * 8);     //                  d 32..63

    f32x4 acc[4];                                  // O^T: 4 d-tiles, col=q per lane
#pragma unroll
    for (int di = 0; di < 4; di++) acc[di] = zero;
    float m = -3.0e38f, lsum = 0.f;

    for (int kc = 0; kc < Sc; kc += 64) {
      __syncthreads();                             // prev chunk compute done
      if (tid < 64) {
        int jj = kc + tid; if (jj >= Sc) jj = Sc - 1;   // clamp-pad: valid finite rows
        rb[tid] = (kl[jj] * NB + n) * EMB + h * DH;
      }
      __syncthreads();                             // rb ready
#pragma unroll
      for (int it = 0; it < 2; it++) {
        int p = it * 256 + tid;                    // 512 pieces
        {                                          // K: [key][d] 16B pieces
          int row = p >> 3, seg = p & 7;
          uint4 u = *(const uint4*)(Kb + rb[row] + seg * 8);
          *(uint4*)(&Ks[row][(seg * 8) ^ ((row & 7) << 3)]) = u;
        }
        {                                          // V^T: gather column d, 8 keys
          int d = p & 63, kg = p >> 6;
          unsigned short v0 = Vb[rb[kg * 8 + 0] + d], v1 = Vb[rb[kg * 8 + 1] + d];
          unsigned short v2 = Vb[rb[kg * 8 + 2] + d], v3 = Vb[rb[kg * 8 + 3] + d];
          unsigned short v4 = Vb[rb[kg * 8 + 4] + d], v5 = Vb[rb[kg * 8 + 5] + d];
          unsigned short v6 = Vb[rb[kg * 8 + 6] + d], v7 = Vb[rb[kg * 8 + 7] + d];
          uint4 u;
          u.x = (uint32_t)v0 | ((uint32_t)v1 << 16);
          u.y = (uint32_t)v2 | ((uint32_t)v3 << 16);
          u.z = (uint32_t)v4 | ((uint32_t)v5 << 16);
          u.w = (uint32_t)v6 | ((uint32_t)v7 << 16);
          *(uint4*)(&Vts[d][(kg * 8) ^ ((d & 7) << 3)]) = u;
        }
      }
      __syncthreads();                             // K/V^T staged

      // S^T = K @ Q^T : 4 key-tiles x 2 d-steps
      f32x4 st[4];
#pragma unroll
      for (int ni = 0; ni < 4; ni++) st[ni] = zero;
#pragma unroll
      for (int ni = 0; ni < 4; ni++) {
        int row = ni * 16 + lq;
        bf16x8 kf0 = *(const bf16x8*)(&Ks[row][(lg * 8) ^ ((row & 7) << 3)]);
        bf16x8 kf1 = *(const bf16x8*)(&Ks[row][(32 + lg * 8) ^ ((row & 7) << 3)]);
        st[ni] = __builtin_amdgcn_mfma_f32_16x16x32_bf16(kf0, qf0, st[ni], 0, 0, 0);
        st[ni] = __builtin_amdgcn_mfma_f32_16x16x32_bf16(kf1, qf1, st[ni], 0, 0, 0);
      }

      // online softmax (per-lane scalar state; clamp-padded keys duplicate valid
      // scores so they cannot change the max; they are zeroed in p below)
      int lim = Sc - kc;
      float cm = -3.0e38f;
#pragma unroll
      for (int ni = 0; ni < 4; ni++) {
        st[ni] = st[ni] * 0.125f;                  // 1/sqrt(64)
#pragma unroll
        for (int r = 0; r < 4; r++) cm = fmaxf(cm, st[ni][r]);
      }
      cm = fmaxf(cm, __shfl_xor(cm, 16, 64));
      cm = fmaxf(cm, __shfl_xor(cm, 32, 64));
      float mn = fmaxf(m, cm);
      float fac = __expf(m - mn);
      m = mn;
      lsum *= fac;
#pragma unroll
      for (int di = 0; di < 4; di++) acc[di] = acc[di] * fac;

      // P^T -> LDS (bf16); lsum over ROUNDED p so O stays a true weighted average
#pragma unroll
      for (int ni = 0; ni < 4; ni++) {
        int kloc = ni * 16 + lg * 4;
        float p0 = (kloc + 0 < lim) ? __expf(st[ni][0] - mn) : 0.f;
        float p1 = (kloc + 1 < lim) ? __expf(st[ni][1] - mn) : 0.f;
        float p2 = (kloc + 2 < lim) ? __expf(st[ni][2] - mn) : 0.f;
        float p3 = (kloc + 3 < lim) ? __expf(st[ni][3] - mn) : 0.f;
        unsigned short b0 = f2bf(p0), b1 = f2bf(p1), b2 = f2bf(p2), b3 = f2bf(p3);
        lsum += bf2f(b0) + bf2f(b1) + bf2f(b2) + bf2f(b3);
        ushort4 u4; u4.x = b0; u4.y = b1; u4.z = b2; u4.w = b3;
        *(ushort4*)(&Pts[wave][lq][kloc ^ ((lq & 7) << 3)]) = u4;
      }

      // O^T += V^T @ P^T : 4 d-tiles x 2 key-steps
#pragma unroll
      for (int ks = 0; ks < 2; ks++) {
        bf16x8 pf = *(const bf16x8*)(&Pts[wave][lq][(ks * 32 + lg * 8) ^ ((lq & 7) << 3)]);
#pragma unroll
        for (int di = 0; di < 4; di++) {
          int row = di * 16 + lq;
          bf16x8 vf = *(const bf16x8*)(&Vts[row][(ks * 32 + lg * 8) ^ ((row & 7) << 3)]);
          acc[di] = __builtin_amdgcn_mfma_f32_16x16x32_bf16(vf, pf, acc[di], 0, 0, 0);
        }
      }
    }

    lsum += __shfl_xor(lsum, 16, 64);
    lsum += __shfl_xor(lsum, 32, 64);
    float rinv = 1.f / lsum;
    if (qq < Lc) {                                 // padded duplicates skip the store
      unsigned short* op = ctx + ((size_t)(n * L_SEQ + lrow)) * EMB + h * DH;
#pragma unroll
      for (int di = 0; di < 4; di++) {
        ushort4 o;
        o.x = f2bf(acc[di][0] * rinv);
        o.y = f2bf(acc[di][1] * rinv);
        o.z = f2bf(acc[di][2] * rinv);
        o.w = f2bf(acc[di][3] * rinv);
        *(ushort4*)(op + di * 16 + lg * 4) = o;    // d = di*16 + 4g + r, contiguous r
      }
    }
  }
}

// Residual + LayerNorm, f32 output. out row r = l*NB+n; proj row = n*L+l. (R9-validated.)
__global__ void __launch_bounds__(256) ln_kernel(
    const float* __restrict__ proj, const float* __restrict__ query,
    const float* __restrict__ gamma, const float* __restrict__ beta,
    float* __restrict__ out)
{
  int r = blockIdx.x;
  int l = r >> 1, n = r & 1;
  int tid = threadIdx.x, wave = tid >> 6, lane = tid & 63;
  float4 p = *(const float4*)(proj + ((size_t)(n * L_SEQ + l)) * EMB + tid * 4);
  float4 qu = *(const float4*)(query + (size_t)r * EMB + tid * 4);
  float res[4] = { p.x + qu.x, p.y + qu.y, p.z + qu.z, p.w + qu.w };
  float s1 = res[0] + res[1] + res[2] + res[3];
  float s2 = res[0] * res[0] + res[1] * res[1] + res[2] * res[2] + res[3] * res[3];
#pragma unroll
  for (int off = 32; off; off >>= 1) {
    s1 += __shfl_xor(s1, off, 64);
    s2 += __shfl_xor(s2, off, 64);
  }
  __shared__ float a1[4], a2[4];
  if (lane == 0) { a1[wave] = s1; a2[wave] = s2; }
  __syncthreads();
  float t1 = a1[0] + a1[1] + a1[2] + a1[3];
  float t2 = a2[0] + a2[1] + a2[2] + a2[3];
  float mu = t1 * (1.f / EMB);
  float var = fmaxf(t2 * (1.f / EMB) - mu * mu, 0.f);
  float rstd = 1.f / sqrtf(var + 1e-5f);
  float4 gu = *(const float4*)(gamma + tid * 4);
  float4 bu = *(const float4*)(beta + tid * 4);
  float4 o;
  o.x = (res[0] - mu) * rstd * gu.x + bu.x;
  o.y = (res[1] - mu) * rstd * gu.y + bu.y;
  o.z = (res[2] - mu) * rstd * gu.z + bu.z;
  o.w = (res[3] - mu) * rstd * gu.w + bu.w;
  *(float4*)(out + (size_t)r * EMB + tid * 4) = o;
}

extern "C" void kernel_launch(void* const* d_in, const int* in_sizes, int n_in,
                              void* d_out, int out_size, void* d_ws, size_t ws_size,
                              hipStream_t stream) {
  const float* query = (const float*)d_in[0];
  const float* key   = (const float*)d_in[1];
  const float* value = (const float*)d_in[2];
  const float* Wq = (const float*)d_in[3];
  const float* bq = (const float*)d_in[4];
  const float* Wk = (const float*)d_in[5];
  const float* bk = (const float*)d_in[6];
  const float* Wv = (const float*)d_in[7];
  const float* bv = (const float*)d_in[8];
  const float* Wo = (const float*)d_in[9];
  const float* bo = (const float*)d_in[10];
  const float* cq = (const float*)d_in[11];
  const float* ck = (const float*)d_in[12];
  const float* gamma = (const float*)d_in[13];
  const float* beta  = (const float*)d_in[14];
  float* out = (float*)d_out;   // f32 output (reference dtype)

  const size_t MB_EL = (size_t)MROWS * EMB;   // 4M elements

  // workspace (~35 MB): control block first, then bf16 tensors; proj aliases Qb+Kb;
  // xbf (bf16 input scratch) aliases ctx (dead until attention); wbf appended (2 MB);
  // prep partials (8 MB) alias Qb (dead until first GEMM, which runs after prep_reduce).
  int* q_cluster = (int*)d_ws;               // 16 KB
  int* k_cluster = q_cluster + MROWS;        // 16 KB
  int* qcount = k_cluster + MROWS;           // 6 x 64 ints contiguous (one memset)
  int* kcount = qcount + 64;
  int* qoff   = kcount + 64;
  int* koff   = qoff + 64;
  int* qfill  = koff + 64;
  int* kfill  = qfill + 64;
  int* qlist  = kfill + 64;                  // [2][2048]
  int* klist  = qlist + MROWS;               // [2][2048]
  double* Wcq = (double*)(klist + MROWS);    // 256 KB (offset 67072, 16B-aligned) [k][c] layout
  double* Wck = Wcq + (size_t)NC * EMB;      // 256 KB [k][c] layout
  double* bdq = Wck + (size_t)NC * EMB;
  double* bdk = bdq + NC;
  unsigned short* Qb  = (unsigned short*)(bdk + NC);  // 8 MB bf16, row = seq*2+n
  unsigned short* Kb  = Qb + MB_EL;                   // 8 MB
  unsigned short* Vb  = Kb + MB_EL;                   // 8 MB
  unsigned short* ctx = Vb + MB_EL;                   // 8 MB, row = n*L+l
  unsigned short* wbf = ctx + MB_EL;                  // 2 MB bf16 weight scratch (reused 4x)
  unsigned short* xbf = ctx;   // bf16 input scratch overlays ctx (dead until attn writes it)
  float* proj = (float*)Qb;    // 16 MB f32 overlays Qb+Kb (dead after attention)
  double* partQ = (double*)Qb; // 4 MB prep partials overlay Qb (consumed before GEMM 1)
  double* partK = partQ + (size_t)16 * NC * EMB;      // 4 MB

  const int W8 = (EMB * EMB) / 8;     // 131072 chunks
  const int X8 = (int)(MB_EL / 8);    // 524288 chunks
  const int CVT_BLK = (W8 + X8 + 255) / 256;   // fused W+X convert grid

  hipMemsetAsync(qcount, 0, 6 * 64 * sizeof(int), stream);

  prep_partial_kernel<<<dim3(16, 16, 2), 256, 0, stream>>>(Wq, cq, Wk, ck, partQ, partK);
  prep_reduce_kernel<<<(2 * NC * EMB) / 256, 256, 0, stream>>>(partQ, partK, Wcq, Wck);
  prep_bd_kernel<<<2, 256, 0, stream>>>(bq, cq, bk, ck, bdq, bdk);

  dim3 gg(EMB / 128, MROWS / 128);
  conv_f2bf_kernel<<<CVT_BLK, 256, 0, stream>>>(Wq, wbf, W8, query, xbf, X8);
  gemm_bt_mfma<<<gg, 256, 0, stream>>>(xbf, wbf, bq, nullptr, Qb);

  conv_f2bf_kernel<<<CVT_BLK, 256, 0, stream>>>(Wk, wbf, W8, key, xbf, X8);
  gemm_bt_mfma<<<gg, 256, 0, stream>>>(xbf, wbf, bk, nullptr, Kb);

  conv_f2bf_kernel<<<CVT_BLK, 256, 0, stream>>>(Wv, wbf, W8, value, xbf, X8);
  gemm_bt_mfma<<<gg, 256, 0, stream>>>(xbf, wbf, bv, nullptr, Vb);

  assign2_kernel<<<dim3(MROWS / 32, 2), 256, 0, stream>>>(
      query, Wcq, bdq, q_cluster, qcount,
      key,   Wck, bdk, k_cluster, kcount);

  scan_kernel<<<1, 64, 0, stream>>>(qcount, kcount, qoff, koff);
  scatter_kernel<<<(2 * MROWS) / 256, 256, 0, stream>>>(q_cluster, k_cluster, qoff, koff,
                                                        qfill, kfill, qlist, klist);
  attn_bucket<<<dim3(NC, NH, NB), 256, 0, stream>>>(Qb, Kb, Vb, qcount, qoff, qlist,
                                                    kcount, koff, klist, ctx);

  conv_f2bf_kernel<<<(W8 + 255) / 256, 256, 0, stream>>>(Wo, wbf, W8, nullptr, nullptr, 0);
  gemm_bt_mfma<<<gg, 256, 0, stream>>>(ctx, wbf, bo, proj, nullptr);
  ln_kernel<<<MROWS, 256, 0, stream>>>(proj, query, gamma, beta, out);
}